// Round 4
// baseline (458.613 us; speedup 1.0000x reference)
//
#include <hip/hip_runtime.h>
#include <math.h>

// ---------------------------------------------------------------------------
// DIM=256 HEADS=16 DHEAD=16 H=12 W=26 (HW=312)  Hk=3 Wk=6 (J=18)  B=256
// q_map[b,c,s] = q[b,(c*56+s)&255]
// Fused design: grid 256 (one block per batch) x 1024 threads (16 waves/CU).
// d_ws holds pre-packed bf16 MFMA A-fragments (setup kernel k0_setup).
// ---------------------------------------------------------------------------

typedef __attribute__((ext_vector_type(8))) short short8;   // 8 bf16
typedef __attribute__((ext_vector_type(4))) float floatx4;

union U16 { uint4 u; short8 s; };

__device__ __forceinline__ unsigned int f2bf(float f) {   // RNE f32->bf16 (low 16)
    unsigned int u = __float_as_uint(f);
    u += 0x7fffu + ((u >> 16) & 1u);
    return u >> 16;
}
__device__ __forceinline__ unsigned int pk2(float a, float b) {
    return f2bf(a) | (f2bf(b) << 16);
}
__device__ __forceinline__ float bf2f(unsigned short v) {
    return __uint_as_float((unsigned int)v << 16);
}

// d_ws layout: uint4-indexed frag tables then float wdwT
#define WSF_W2 16384            // uint4 index
#define WSF_W3 16896            // uint4 index
#define WSF_DW 68096            // float index: wdwT[36][256]

// ===========================================================================
// k0_setup: pre-pack weights into MFMA-fragment-linear layouts.
//   wk/wv frags: entry id = m2*8192 + mt*512 + ks*64 + lane  -> uint4 (8 bf16)
//                A[m = mt*16 + (lane&15)][k = ks*32 + (lane>>4)*8 + e]
//   w2F: 16384 + mt*128 + ks*64 + lane ; w3F: 16896 + ks*64 + lane
//   wdwT[i*256 + c] = w_dw[c*36 + i]
// ===========================================================================
__global__ __launch_bounds__(256) void k0_setup(
    const float* __restrict__ wk, const float* __restrict__ wv,
    const float* __restrict__ cw2, const float* __restrict__ cw3,
    const float* __restrict__ w_dw, unsigned int* __restrict__ ws)
{
    const int t = blockIdx.x * 256 + threadIdx.x;   // 16384 threads
    uint4* ws4 = (uint4*)ws;
    {
        const int m2 = t >> 13;
        const int r = t & 8191;
        const int mt = r >> 9, ks = (r >> 6) & 7, lane = r & 63;
        const int nn = lane & 15, qd = lane >> 4;
        const float* src = (m2 ? wv : wk) + (mt * 16 + nn) * 256 + ks * 32 + qd * 8;
        uint4 o;
        o.x = pk2(src[0], src[1]); o.y = pk2(src[2], src[3]);
        o.z = pk2(src[4], src[5]); o.w = pk2(src[6], src[7]);
        ws4[t] = o;
    }
    if (t < 512) {
        const int mt = t >> 7, ks = (t >> 6) & 1, lane = t & 63;
        const int nn = lane & 15, qd = lane >> 4;
        const float* src = cw2 + (mt * 16 + nn) * 64 + ks * 32 + qd * 8;
        uint4 o;
        o.x = pk2(src[0], src[1]); o.y = pk2(src[2], src[3]);
        o.z = pk2(src[4], src[5]); o.w = pk2(src[6], src[7]);
        ws4[WSF_W2 + t] = o;
    }
    if (t < 128) {
        const int ks = t >> 6, lane = t & 63;
        const int nn = lane & 15, qd = lane >> 4;
        const float* src = cw3 + nn * 64 + ks * 32 + qd * 8;
        uint4 o;
        o.x = pk2(src[0], src[1]); o.y = pk2(src[2], src[3]);
        o.z = pk2(src[4], src[5]); o.w = pk2(src[6], src[7]);
        ws4[WSF_W3 + t] = o;
    }
    float* wsf = (float*)ws;
    for (int k = t; k < 9216; k += 16384) {
        const int c = k / 36, i = k - c * 36;
        wsf[WSF_DW + i * 256 + c] = w_dw[k];
    }
}

// ===========================================================================
// k_fused: whole forward for one batch element per block. 1024 threads.
// ===========================================================================
__global__ __launch_bounds__(1024, 4) void k_fused(
    const float* __restrict__ x, const float* __restrict__ q,
    const float* __restrict__ b_dw, const float* __restrict__ w_pw,
    const float* __restrict__ cw1, const float* __restrict__ cb1,
    const float* __restrict__ cb2, const float* __restrict__ cb3,
    const float* __restrict__ conv_w, const float* __restrict__ conv_b,
    const float* __restrict__ w_out, const float* __restrict__ b_out,
    const float* __restrict__ ln_g, const float* __restrict__ ln_b,
    const unsigned int* __restrict__ ws, float* __restrict__ out)
{
    const int b = blockIdx.x, tid = threadIdx.x;
    const int w = tid >> 6, lane = tid & 63;       // 16 waves
    const int n = lane & 15, qd = lane >> 4;
    const int c = tid & 255, g = tid >> 8;         // 4 channel-groups

    // ---- persistent LDS (~19.9 KB) ----
    __shared__ float qf_s[256];
    __shared__ unsigned short q_sb[256];            // bf16(q*0.25)
    __shared__ unsigned short v_sb[5120];           // v bf16 [256][20]
    __shared__ float F0[468], F1[216];              // log tables [26][18], [12][18]
    __shared__ unsigned int lutxy[312];             // ix | iy<<16
    __shared__ float off_s[36], n0_s[18], n1_s[18];
    __shared__ float sx0[18], sy0[18], swx[18], swy[18];
    __shared__ float wA_s[288], b2_s[64], b3_s[16];
    __shared__ __align__(16) float m_s[256];
    __shared__ float pooled_s[256], redb[24];
    // ---- union region (89344 B) ----
    __shared__ __align__(16) unsigned char UB[89344];
    float* S_ = (float*)UB;                          // [32 il][18 j][21 h] f32 (48384B)
    unsigned short* kvT = (unsigned short*)UB;       // [18 j][264 c] bf16 (9504B)
    float* qsw = (float*)UB;                         // 16 copies x 258 (16512B)
    float* t_s = (float*)(UB + 16512);               // [18 p][256 c] (18432B)
    unsigned short* k_sb = (unsigned short*)(UB + 16512);  // k bf16 [256][20]
    unsigned int* h2w = (unsigned int*)(UB + 48384); // per-wave h2 [16][16][40] (40960B)
    float* wred = (float*)UB;                        // [32 slot][16 h][18 j] (36864B)

    const uint4* ws4 = (const uint4*)ws;
    const float* wsf = (const float*)ws;

    // ---- stage 0: q, swizzled q copies, lut, biases ----
    if (tid < 256) {
        const float qv = q[b * 256 + tid];
        qf_s[tid] = qv;
        q_sb[tid] = (unsigned short)f2bf(qv * 0.25f);
    }
    for (int u = tid; u < 4128; u += 1024) {
        const int r = u / 258, i = u - r * 258;
        qsw[u] = (i < 256) ? q[b * 256 + i] : 0.f;
    }
    if (tid < 312) {
        const int iy = tid / 26;
        lutxy[tid] = (unsigned int)(tid - iy * 26) | ((unsigned int)iy << 16);
    }
    if (tid < 64) b2_s[tid] = cb2[tid];
    if (tid < 16) b3_s[tid] = cb3[tid];
    __syncthreads();

    // ---- depthwise conv 6x6 s4 p1 + GELU -> t_s (g handles p = g, g+4, ...) ----
    {
        float wreg[36];
        #pragma unroll
        for (int i = 0; i < 36; ++i) wreg[i] = wsf[WSF_DW + i * 256 + c];
        const float bv = b_dw[c];
        const int cb = (c * 56) & 255;
        const int cp = (c & 15) * 258;
        for (int p = g; p < 18; p += 4) {
            const int jh = p / 6, jw = p - jh * 6;
            float acc = bv;
            for (int kh = 0; kh < 6; ++kh) {
                const int ih = jh * 4 - 1 + kh;
                if (ih < 0 || ih >= 12) continue;
                const int rb = ih * 26;
                for (int kw = 0; kw < 6; ++kw) {
                    const int iw = jw * 4 - 1 + kw;
                    if (iw < 0 || iw >= 26) continue;
                    acc += wreg[kh * 6 + kw] * qsw[cp + ((cb + rb + iw) & 255)];
                }
            }
            t_s[p * 256 + c] = 0.5f * acc * (1.0f + erff(acc * 0.70710678118654752f));
        }
    }
    __syncthreads();

    // ---- offsets: 36 dots over 256 channels (one per wave, 2-3 rounds) ----
    for (int oi = w; oi < 36; oi += 16) {
        const int o = oi / 18, p = oi - o * 18;
        float s = 0.f;
        for (int cc = lane; cc < 256; cc += 64) s += w_pw[o * 256 + cc] * t_s[p * 256 + cc];
        for (int d = 32; d > 0; d >>= 1) s += __shfl_down(s, d, 64);
        if (lane == 0) off_s[oi] = 4.0f * tanhf(s);
    }
    __syncthreads();

    // ---- grid coords + bilinear params ----
    if (tid < 18) {
        const int j = tid, jh = j / 6, jw = j - jh * 6;
        const float vg0 = (float)jw + off_s[j];
        const float vg1 = (float)jh + off_s[18 + j];
        const float n0 = 2.0f * vg0 / 2.0f - 1.0f;
        const float n1 = 2.0f * vg1 / 5.0f - 1.0f;
        n0_s[j] = n0; n1_s[j] = n1;
        const float xp = ((n0 + 1.0f) * 26.0f - 1.0f) * 0.5f;
        const float yp = ((n1 + 1.0f) * 12.0f - 1.0f) * 0.5f;
        const float x0 = floorf(xp), y0 = floorf(yp);
        sx0[j] = x0; sy0[j] = y0; swx[j] = xp - x0; swy[j] = yp - y0;
    }
    __syncthreads();

    // ---- bilinear sample -> kvT bf16 [j][264]; build F0/F1 log tables ----
    {
        const float* xb = x + ((size_t)b * 256 + c) * 312;
        for (int j = g; j < 18; j += 4) {
            const int x0 = (int)sx0[j], y0 = (int)sy0[j];
            const int x1 = x0 + 1, y1 = y0 + 1;
            const float wx1 = swx[j], wy1 = swy[j];
            const float wx0 = 1.f - wx1, wy0 = 1.f - wy1;
            const bool xv0 = (x0 >= 0) & (x0 < 26), xv1 = (x1 >= 0) & (x1 < 26);
            const bool yv0 = (y0 >= 0) & (y0 < 12), yv1 = (y1 >= 0) & (y1 < 12);
            const float v00 = (xv0 & yv0) ? xb[y0 * 26 + x0] : 0.f;
            const float v01 = (xv1 & yv0) ? xb[y0 * 26 + x1] : 0.f;
            const float v10 = (xv0 & yv1) ? xb[y1 * 26 + x0] : 0.f;
            const float v11 = (xv1 & yv1) ? xb[y1 * 26 + x1] : 0.f;
            const float val = wy0 * (wx0 * v00 + wx1 * v01) + wy1 * (wx0 * v10 + wx1 * v11);
            kvT[j * 264 + c] = (unsigned short)f2bf(val);
        }
    }
    if (tid < 684) {
        if (tid < 468) {
            const int ixv = tid / 18, j = tid - ixv * 18;
            const float p0 = (float)ixv * (2.0f / 11.0f) - 1.0f - n0_s[j];
            F0[tid] = copysignf(__logf(1.0f + fabsf(p0)), p0);
        } else {
            const int u2 = tid - 468;
            const int iyv = u2 / 18, j = u2 - iyv * 18;
            const float p1 = (float)iyv * (2.0f / 25.0f) - 1.0f - n1_s[j];
            F1[u2] = copysignf(__logf(1.0f + fabsf(p1)), p1);
        }
    }
    __syncthreads();

    // ---- k/v projection via MFMA: wave w -> matrix (w&1), mtb = w>>1 ----
    {
        const int m2 = w & 1, mtb = w >> 1;
        floatx4 pa[2][2];
        #pragma unroll
        for (int a = 0; a < 2; ++a) {
            pa[a][0] = (floatx4){0.f, 0.f, 0.f, 0.f};
            pa[a][1] = (floatx4){0.f, 0.f, 0.f, 0.f};
        }
        for (int ks = 0; ks < 8; ++ks) {
            U16 b0, b1;
            b0.u = *(const uint4*)(kvT + n * 264 + ks * 32 + qd * 8);
            b1.u = make_uint4(0u, 0u, 0u, 0u);
            if (n < 2) b1.u = *(const uint4*)(kvT + (16 + n) * 264 + ks * 32 + qd * 8);
            #pragma unroll
            for (int mtl = 0; mtl < 2; ++mtl) {
                const int mt = mtb + mtl * 8;
                U16 A; A.u = ws4[m2 * 8192 + mt * 512 + ks * 64 + lane];
                pa[mtl][0] = __builtin_amdgcn_mfma_f32_16x16x32_bf16(A.s, b0.s, pa[mtl][0], 0, 0, 0);
                pa[mtl][1] = __builtin_amdgcn_mfma_f32_16x16x32_bf16(A.s, b1.s, pa[mtl][1], 0, 0, 0);
            }
        }
        unsigned short* dst = m2 ? v_sb : k_sb;
        #pragma unroll
        for (int mtl = 0; mtl < 2; ++mtl) {
            const int mt = mtb + mtl * 8;
            #pragma unroll
            for (int r = 0; r < 4; ++r) {
                const int o = mt * 16 + qd * 4 + r;
                dst[o * 20 + n] = (unsigned short)f2bf(pa[mtl][0][r]);
                if (n < 2) dst[o * 20 + 16 + n] = (unsigned short)f2bf(pa[mtl][1][r]);
            }
        }
    }
    __syncthreads();

    // ---- Bk fragments for sim (wave w = head w) ----
    uint4 BkU[2];
    #pragma unroll
    for (int jt = 0; jt < 2; ++jt) {
        unsigned int u0 = 0, u1 = 0, u2 = 0, u3 = 0;
        if (qd < 2 && (jt == 0 || n < 2)) {
            const int j = jt * 16 + n;
            const int cb0 = (w * 16 + qd * 8) * 20 + j;
            u0 = (unsigned)k_sb[cb0] | ((unsigned)k_sb[cb0 + 20] << 16);
            u1 = (unsigned)k_sb[cb0 + 40] | ((unsigned)k_sb[cb0 + 60] << 16);
            u2 = (unsigned)k_sb[cb0 + 80] | ((unsigned)k_sb[cb0 + 100] << 16);
            u3 = (unsigned)k_sb[cb0 + 120] | ((unsigned)k_sb[cb0 + 140] << 16);
        }
        BkU[jt] = make_uint4(u0, u1, u2, u3);
    }
    __syncthreads();   // k_sb dead; S_/h2w regions live from here

    // ---- per-lane constants for the chunk loop ----
    uint4 W2f[4][2], W3f[2];
    #pragma unroll
    for (int mtl = 0; mtl < 4; ++mtl)
        #pragma unroll
        for (int ks = 0; ks < 2; ++ks)
            W2f[mtl][ks] = ws4[WSF_W2 + mtl * 128 + ks * 64 + lane];
    W3f[0] = ws4[WSF_W3 + lane];
    W3f[1] = ws4[WSF_W3 + 64 + lane];

    float W1a[16], W1b[16], B1r[16];
    #pragma unroll
    for (int kk = 0; kk < 16; ++kk) {
        const int kid = (kk < 8) ? (qd * 8 + kk) : (32 + qd * 8 + kk - 8);
        W1a[kk] = cw1[kid * 2]; W1b[kk] = cw1[kid * 2 + 1]; B1r[kk] = cb1[kid];
    }

    float wAcc[18];
    #pragma unroll
    for (int j = 0; j < 18; ++j) wAcc[j] = 0.f;

    // ---- chunk loop: 10 chunks of 32 i's (last 24) ----
    for (int ch = 0; ch < 10; ++ch) {
        const int ibase = ch * 32;
        const int CI = (ch == 9) ? 24 : 32;

        // (a) sim: wave = head w; 2 i-groups x 2 j-tiles
        #pragma unroll
        for (int ig = 0; ig < 2; ++ig) {
            unsigned int a0 = 0, a1 = 0, a2 = 0, a3u = 0;
            if (qd < 2) {
                const int base = w * 16 + qd * 8;
                const int ii = ibase + ig * 16 + n;
                a0 = (unsigned)q_sb[((base + 0) * 56 + ii) & 255] |
                     ((unsigned)q_sb[((base + 1) * 56 + ii) & 255] << 16);
                a1 = (unsigned)q_sb[((base + 2) * 56 + ii) & 255] |
                     ((unsigned)q_sb[((base + 3) * 56 + ii) & 255] << 16);
                a2 = (unsigned)q_sb[((base + 4) * 56 + ii) & 255] |
                     ((unsigned)q_sb[((base + 5) * 56 + ii) & 255] << 16);
                a3u = (unsigned)q_sb[((base + 6) * 56 + ii) & 255] |
                      ((unsigned)q_sb[((base + 7) * 56 + ii) & 255] << 16);
            }
            U16 Af; Af.u = make_uint4(a0, a1, a2, a3u);
            #pragma unroll
            for (int jt = 0; jt < 2; ++jt) {
                U16 Bf; Bf.u = BkU[jt];
                floatx4 D = {0.f, 0.f, 0.f, 0.f};
                D = __builtin_amdgcn_mfma_f32_16x16x32_bf16(Af.s, Bf.s, D, 0, 0, 0);
                const int j = jt * 16 + n;
                if (j < 18) {
                    #pragma unroll
                    for (int r = 0; r < 4; ++r)
                        S_[((ig * 16 + qd * 4 + r) * 18 + j) * 21 + w] = D[r];
                }
            }
        }
        __syncthreads();

        // (b) CPB MLP + logits; tile t = (ig, j), 36 tiles over 16 waves
        for (int t = w; t < 36; t += 16) {
            const int ig = (t >= 18) ? 1 : 0;
            const int j = t - ig * 18;
            const int i0r = ibase + ig * 16 + n;
            const unsigned int lv = lutxy[(i0r < 312) ? i0r : 311];
            const int ix = (int)(lv & 0xffffu), iy = (int)(lv >> 16);
            const float f0 = F0[ix * 18 + j];
            const float f1 = F1[iy * 18 + j];
            unsigned int uu[8];
            #pragma unroll
            for (int kp = 0; kp < 8; ++kp) {
                const float ha = fmaxf(fmaf(W1a[2 * kp], f0, fmaf(W1b[2 * kp], f1, B1r[2 * kp])), 0.f);
                const float hb = fmaxf(fmaf(W1a[2 * kp + 1], f0, fmaf(W1b[2 * kp + 1], f1, B1r[2 * kp + 1])), 0.f);
                uu[kp] = pk2(ha, hb);
            }
            U16 ub0, ub1;
            ub0.u = make_uint4(uu[0], uu[1], uu[2], uu[3]);
            ub1.u = make_uint4(uu[4], uu[5], uu[6], uu[7]);
            unsigned int* hw = h2w + w * 640 + n * 40;
            #pragma unroll
            for (int mtl = 0; mtl < 4; ++mtl) {
                U16 A0, A1; A0.u = W2f[mtl][0]; A1.u = W2f[mtl][1];
                floatx4 acc = {0.f, 0.f, 0.f, 0.f};
                acc = __builtin_amdgcn_mfma_f32_16x16x32_bf16(A0.s, ub0.s, acc, 0, 0, 0);
                acc = __builtin_amdgcn_mfma_f32_16x16x32_bf16(A1.s, ub1.s, acc, 0, 0, 0);
                const float e0 = fmaxf(acc[0] + b2_s[mtl * 16 + qd * 4 + 0], 0.f);
                const float e1 = fmaxf(acc[1] + b2_s[mtl * 16 + qd * 4 + 1], 0.f);
                const float e2 = fmaxf(acc[2] + b2_s[mtl * 16 + qd * 4 + 2], 0.f);
                const float e3 = fmaxf(acc[3] + b2_s[mtl * 16 + qd * 4 + 3], 0.f);
                hw[mtl * 8 + qd * 2]     = pk2(e0, e1);
                hw[mtl * 8 + qd * 2 + 1] = pk2(e2, e3);
            }
            U16 uc0, uc1;
            uc0.u = *(const uint4*)(hw + qd * 4);
            uc1.u = *(const uint4*)(hw + 16 + qd * 4);
            floatx4 a3 = {0.f, 0.f, 0.f, 0.f};
            {
                U16 A0, A1; A0.u = W3f[0]; A1.u = W3f[1];
                a3 = __builtin_amdgcn_mfma_f32_16x16x32_bf16(A0.s, uc0.s, a3, 0, 0, 0);
                a3 = __builtin_amdgcn_mfma_f32_16x16x32_bf16(A1.s, uc1.s, a3, 0, 0, 0);
            }
            float* sp = S_ + ((ig * 16 + n) * 18 + j) * 21 + qd * 4;
            #pragma unroll
            for (int r = 0; r < 4; ++r) sp[r] = a3[r] + b3_s[qd * 4 + r] + sp[r];
        }
        __syncthreads();

        // (c) softmax over j + conv-weighted accumulation (512 threads)
        if (tid < 512) {
            const int il = tid >> 4, h = tid & 15;
            if (il < CI) {
                float lv[18];
                #pragma unroll
                for (int j = 0; j < 18; ++j) lv[j] = S_[(il * 18 + j) * 21 + h];
                float m = lv[0];
                #pragma unroll
                for (int j = 1; j < 18; ++j) m = fmaxf(m, lv[j]);
                float s = 0.f;
                #pragma unroll
                for (int j = 0; j < 18; ++j) { lv[j] = __expf(lv[j] - m); s += lv[j]; }
                const float wgt = conv_w[ibase + il] / s;
                #pragma unroll
                for (int j = 0; j < 18; ++j) wAcc[j] = fmaf(wgt, lv[j], wAcc[j]);
            }
        }
        __syncthreads();
    }

    // ---- reduce wAcc over 32 il-slots -> wA_s[h][j]; conv_w sum ----
    if (tid < 512) {
        const int slot = tid >> 4, h = tid & 15;
        #pragma unroll
        for (int j = 0; j < 18; ++j) wred[(slot * 16 + h) * 18 + j] = wAcc[j];
    }
    {
        float v = 0.f;
        for (int u = tid; u < 312; u += 1024) v += conv_w[u];
        for (int d = 32; d > 0; d >>= 1) v += __shfl_down(v, d, 64);
        if (lane == 0) redb[w] = v;
    }
    __syncthreads();
    for (int u = tid; u < 288; u += 1024) {
        const int h = u / 18, j = u - h * 18;
        float s = 0.f;
        #pragma unroll
        for (int sl = 0; sl < 32; ++sl) s += wred[(sl * 16 + h) * 18 + j];
        wA_s[u] = s;
    }
    __syncthreads();

    // ---- m[c] = sum_j wA[h][j] * v[c][j] ----
    if (tid < 256) {
        const int hb = (tid >> 4) * 18;
        float acc = 0.f;
        #pragma unroll
        for (int j = 0; j < 18; ++j) acc += wA_s[hb + j] * bf2f(v_sb[tid * 20 + j]);
        m_s[tid] = acc;
    }
    __syncthreads();

    float Ssum = 0.f;
    #pragma unroll
    for (int i = 0; i < 16; ++i) Ssum += redb[i];

    // ---- pooled = w_out . m  (16 waves x 16 rows, coalesced float4) ----
    {
        const float4 mm = *(const float4*)(m_s + lane * 4);
        for (int ol = 0; ol < 16; ++ol) {
            const int o = w * 16 + ol;
            const float4 wq = *(const float4*)(w_out + o * 256 + lane * 4);
            float d = wq.x * mm.x + wq.y * mm.y + wq.z * mm.z + wq.w * mm.w;
            for (int dd = 32; dd > 0; dd >>= 1) d += __shfl_down(d, dd, 64);
            if (lane == 0) pooled_s[o] = d;
        }
    }
    __syncthreads();

    // ---- residual + LayerNorm (first 4 waves) ----
    if (tid < 256) {
        const float y = pooled_s[tid] + b_out[tid] * Ssum + conv_b[0] + qf_s[tid];
        float s1 = y, s2 = y * y;
        for (int d = 32; d > 0; d >>= 1) { s1 += __shfl_down(s1, d, 64); s2 += __shfl_down(s2, d, 64); }
        if (lane == 0) { redb[16 + w] = s1; redb[20 + w] = s2; }
    }
    __syncthreads();
    if (tid < 256) {
        const float y = pooled_s[tid] + b_out[tid] * Ssum + conv_b[0] + qf_s[tid];
        const float S1 = redb[16] + redb[17] + redb[18] + redb[19];
        const float S2 = redb[20] + redb[21] + redb[22] + redb[23];
        const float mu = S1 * (1.0f / 256.0f);
        const float var = S2 * (1.0f / 256.0f) - mu * mu;
        out[b * 256 + tid] = (y - mu) * rsqrtf(var + 1e-5f) * ln_g[tid] + ln_b[tid];
    }
}

// ===========================================================================
extern "C" void kernel_launch(void* const* d_in, const int* in_sizes, int n_in,
                              void* d_out, int out_size, void* d_ws, size_t ws_size,
                              hipStream_t stream) {
    const float* x       = (const float*)d_in[0];
    const float* q       = (const float*)d_in[1];
    const float* w_dw    = (const float*)d_in[2];
    const float* b_dwp   = (const float*)d_in[3];
    const float* w_pw    = (const float*)d_in[4];
    const float* wk      = (const float*)d_in[5];
    const float* wv      = (const float*)d_in[6];
    const float* w_out   = (const float*)d_in[7];
    const float* b_out   = (const float*)d_in[8];
    const float* cw1     = (const float*)d_in[9];
    const float* cb1     = (const float*)d_in[10];
    const float* cw2     = (const float*)d_in[11];
    const float* cb2     = (const float*)d_in[12];
    const float* cw3     = (const float*)d_in[13];
    const float* cb3     = (const float*)d_in[14];
    const float* conv_w  = (const float*)d_in[15];
    const float* conv_b  = (const float*)d_in[16];
    const float* ln_g    = (const float*)d_in[17];
    const float* ln_b    = (const float*)d_in[18];
    float* out = (float*)d_out;
    unsigned int* ws = (unsigned int*)d_ws;

    k0_setup<<<64, 256, 0, stream>>>(wk, wv, cw2, cw3, w_dw, ws);
    k_fused<<<256, 1024, 0, stream>>>(x, q, b_dwp, w_pw, cw1, cb1, cb2, cb3,
                                      conv_w, conv_b, w_out, b_out, ln_g, ln_b,
                                      (const unsigned int*)ws, out);
}

// Round 5
// 340.712 us; speedup vs baseline: 1.3460x; 1.3460x over previous
//
#include <hip/hip_runtime.h>
#include <math.h>

// ---------------------------------------------------------------------------
// DIM=256 HEADS=16 DHEAD=16 H=12 W=26 (HW=312)  Hk=3 Wk=6 (J=18)  B=256
// q_map[b,c,s] = q[b,(c*56+s)&255]
// Round 5: grid (2 i-halves, 256 batches) x 512 thr  -> 2 blocks/CU, 16 waves.
// __launch_bounds__ 2nd arg kept at 2: r4 showed (1024,4) => 64-VGPR cap =>
// catastrophic spills (889 MB HBM traffic). (512,2) => VGPR 116, no spill.
// ---------------------------------------------------------------------------

typedef __attribute__((ext_vector_type(8))) short short8;   // 8 bf16
typedef __attribute__((ext_vector_type(4))) float floatx4;

union U16 { uint4 u; short8 s; };

__device__ __forceinline__ unsigned int f2bf(float f) {   // RNE f32->bf16 (low 16)
    unsigned int u = __float_as_uint(f);
    u += 0x7fffu + ((u >> 16) & 1u);
    return u >> 16;
}
__device__ __forceinline__ unsigned int pk2(float a, float b) {
    return f2bf(a) | (f2bf(b) << 16);
}

// d_ws layout: uint4-indexed frag tables, then float regions
#define WSF_W2 16384            // uint4 index
#define WSF_W3 16896            // uint4 index
#define WSF_DW 68096            // float index: wdwT[36][256]
#define WSF_V  80000            // float index: v fp32 [256 b][256 o][18 j]
#define WSF_WA 1260000          // float index: wA [256 b][16 h][18 j]

// ===========================================================================
// k0_setup: pre-pack weights into MFMA-fragment-linear layouts + zero wA.
// ===========================================================================
__global__ __launch_bounds__(256) void k0_setup(
    const float* __restrict__ wk, const float* __restrict__ wv,
    const float* __restrict__ cw2, const float* __restrict__ cw3,
    const float* __restrict__ w_dw, unsigned int* __restrict__ ws)
{
    const int t = blockIdx.x * 256 + threadIdx.x;   // 16384 threads
    uint4* ws4 = (uint4*)ws;
    {
        const int m2 = t >> 13;
        const int r = t & 8191;
        const int mt = r >> 9, ks = (r >> 6) & 7, lane = r & 63;
        const int nn = lane & 15, qd = lane >> 4;
        const float* src = (m2 ? wv : wk) + (mt * 16 + nn) * 256 + ks * 32 + qd * 8;
        uint4 o;
        o.x = pk2(src[0], src[1]); o.y = pk2(src[2], src[3]);
        o.z = pk2(src[4], src[5]); o.w = pk2(src[6], src[7]);
        ws4[t] = o;
    }
    if (t < 512) {
        const int mt = t >> 7, ks = (t >> 6) & 1, lane = t & 63;
        const int nn = lane & 15, qd = lane >> 4;
        const float* src = cw2 + (mt * 16 + nn) * 64 + ks * 32 + qd * 8;
        uint4 o;
        o.x = pk2(src[0], src[1]); o.y = pk2(src[2], src[3]);
        o.z = pk2(src[4], src[5]); o.w = pk2(src[6], src[7]);
        ws4[WSF_W2 + t] = o;
    }
    if (t < 128) {
        const int ks = t >> 6, lane = t & 63;
        const int nn = lane & 15, qd = lane >> 4;
        const float* src = cw3 + nn * 64 + ks * 32 + qd * 8;
        uint4 o;
        o.x = pk2(src[0], src[1]); o.y = pk2(src[2], src[3]);
        o.z = pk2(src[4], src[5]); o.w = pk2(src[6], src[7]);
        ws4[WSF_W3 + t] = o;
    }
    float* wsf = (float*)ws;
    for (int k = t; k < 9216; k += 16384) {
        const int c = k / 36, i = k - c * 36;
        wsf[WSF_DW + i * 256 + c] = w_dw[k];
    }
    for (int u = t; u < 73728; u += 16384) wsf[WSF_WA + u] = 0.f;
}

// ===========================================================================
// k_fused: prologue + half the i-range per block; wA partial via atomicAdd.
// ===========================================================================
__global__ __launch_bounds__(512, 2) void k_fused(
    const float* __restrict__ x, const float* __restrict__ q,
    const float* __restrict__ b_dw, const float* __restrict__ w_pw,
    const float* __restrict__ cw1, const float* __restrict__ cb1,
    const float* __restrict__ cb2, const float* __restrict__ cb3,
    const float* __restrict__ conv_w,
    unsigned int* __restrict__ ws)
{
    const int ib = blockIdx.x;                     // i-half: [ib*160, ...)
    const int b = blockIdx.y, tid = threadIdx.x;
    const int w = tid >> 6, lane = tid & 63;
    const int n = lane & 15, qd = lane >> 4;

    // ---- persistent LDS ----
    __shared__ unsigned short q_sb[256];            // bf16(q*0.25)
    __shared__ float F0[468], F1[216];              // log tables [26][18], [12][18]
    __shared__ unsigned int lutxy[312];             // ix | iy<<16
    __shared__ float off_s[36], n0_s[18], n1_s[18];
    __shared__ float sx0[18], sy0[18], swx[18], swy[18];
    __shared__ float b2_s[64], b3_s[16];
    // ---- union region (38464 B) ----
    __shared__ __align__(16) unsigned char UB[38464];
    float* S_ = (float*)UB;                          // [16 il][18 j][17 h] f32 19584B
    unsigned short* kvT = (unsigned short*)UB;       // [18 j][264 c] bf16 (9504B)
    float* qsw = (float*)UB;                         // 16 copies x 258 (16512B)
    float* t_s = (float*)(UB + 16512);               // [18 p][256 c] (18432B)
    unsigned short* k_sb = (unsigned short*)(UB + 16512);  // k bf16 [256][20]
    unsigned int* h2w = (unsigned int*)(UB + 20000); // per-wave h2 [8][16][36]
    float* wred = (float*)UB;                        // [16 slot][16 h][18 j] 18432B

    const uint4* ws4 = (const uint4*)ws;
    const float* wsf = (const float*)ws;
    float* wsw = (float*)ws;

    // ---- per-lane constant registers ----
    uint4 W2f[4][2], W3f[2];
    #pragma unroll
    for (int mtl = 0; mtl < 4; ++mtl)
        #pragma unroll
        for (int ks = 0; ks < 2; ++ks)
            W2f[mtl][ks] = ws4[WSF_W2 + mtl * 128 + ks * 64 + lane];
    W3f[0] = ws4[WSF_W3 + lane];
    W3f[1] = ws4[WSF_W3 + 64 + lane];

    float W1a[16], W1b[16], B1r[16];
    #pragma unroll
    for (int kk = 0; kk < 16; ++kk) {
        const int kid = (kk < 8) ? (qd * 8 + kk) : (32 + qd * 8 + kk - 8);
        W1a[kk] = cw1[kid * 2]; W1b[kk] = cw1[kid * 2 + 1]; B1r[kk] = cb1[kid];
    }

    // ---- stage 0 ----
    if (tid < 256) q_sb[tid] = (unsigned short)f2bf(q[b * 256 + tid] * 0.25f);
    for (int u = tid; u < 4128; u += 512) {
        const int r = u / 258, i = u - r * 258;
        qsw[u] = (i < 256) ? q[b * 256 + i] : 0.f;
    }
    if (tid < 312) {
        const int iy = tid / 26;
        lutxy[tid] = (unsigned int)(tid - iy * 26) | ((unsigned int)iy << 16);
    }
    if (tid < 64) b2_s[tid] = cb2[tid];
    if (tid < 16) b3_s[tid] = cb3[tid];
    __syncthreads();

    // ---- depthwise conv 6x6 s4 p1 + GELU -> t_s ----
    {
        const int c = tid & 255, g = tid >> 8;     // g: jw-half
        float wreg[36];
        #pragma unroll
        for (int i = 0; i < 36; ++i) wreg[i] = wsf[WSF_DW + i * 256 + c];
        float acc[9];
        const float bv = b_dw[c];
        #pragma unroll
        for (int a = 0; a < 9; ++a) acc[a] = bv;
        const int cb = (c * 56) & 255;
        const int cp = (c & 15) * 258;
        for (int jh = 0; jh < 3; ++jh) {
            for (int kh = 0; kh < 6; ++kh) {
                const int ih = jh * 4 - 1 + kh;
                if (ih < 0 || ih >= 12) continue;
                const int rb = ih * 26;
                #pragma unroll
                for (int jwl = 0; jwl < 3; ++jwl) {
                    const int jw = g * 3 + jwl;
                    #pragma unroll
                    for (int kw = 0; kw < 6; ++kw) {
                        const int iw = jw * 4 - 1 + kw;
                        if (iw < 0 || iw >= 26) continue;
                        acc[jh * 3 + jwl] += wreg[kh * 6 + kw] * qsw[cp + ((cb + rb + iw) & 255)];
                    }
                }
            }
        }
        #pragma unroll
        for (int a = 0; a < 9; ++a) {
            const int jh = a / 3, jwl = a - jh * 3;
            const int p = jh * 6 + g * 3 + jwl;
            const float v = acc[a];
            t_s[p * 256 + c] = 0.5f * v * (1.0f + erff(v * 0.70710678118654752f));
        }
    }
    __syncthreads();

    // ---- offsets: 36 dots over 256 channels ----
    for (int oi = w; oi < 36; oi += 8) {
        const int o = oi / 18, p = oi - o * 18;
        float s = 0.f;
        for (int c = lane; c < 256; c += 64) s += w_pw[o * 256 + c] * t_s[p * 256 + c];
        for (int d = 32; d > 0; d >>= 1) s += __shfl_down(s, d, 64);
        if (lane == 0) off_s[oi] = 4.0f * tanhf(s);
    }
    __syncthreads();

    // ---- grid coords + bilinear params ----
    if (tid < 18) {
        const int j = tid, jh = j / 6, jw = j - jh * 6;
        const float vg0 = (float)jw + off_s[j];
        const float vg1 = (float)jh + off_s[18 + j];
        const float n0 = 2.0f * vg0 / 2.0f - 1.0f;
        const float n1 = 2.0f * vg1 / 5.0f - 1.0f;
        n0_s[j] = n0; n1_s[j] = n1;
        const float xp = ((n0 + 1.0f) * 26.0f - 1.0f) * 0.5f;
        const float yp = ((n1 + 1.0f) * 12.0f - 1.0f) * 0.5f;
        const float x0 = floorf(xp), y0 = floorf(yp);
        sx0[j] = x0; sy0[j] = y0; swx[j] = xp - x0; swy[j] = yp - y0;
    }
    __syncthreads();

    // ---- bilinear sample -> kvT bf16 [j][264]; F0/F1 log tables ----
    {
        const int c = tid & 255, g = tid >> 8;
        const float* xb = x + ((size_t)b * 256 + c) * 312;
        for (int jj = 0; jj < 9; ++jj) {
            const int j = g * 9 + jj;
            const int x0 = (int)sx0[j], y0 = (int)sy0[j];
            const int x1 = x0 + 1, y1 = y0 + 1;
            const float wx1 = swx[j], wy1 = swy[j];
            const float wx0 = 1.f - wx1, wy0 = 1.f - wy1;
            const bool xv0 = (x0 >= 0) & (x0 < 26), xv1 = (x1 >= 0) & (x1 < 26);
            const bool yv0 = (y0 >= 0) & (y0 < 12), yv1 = (y1 >= 0) & (y1 < 12);
            const float v00 = (xv0 & yv0) ? xb[y0 * 26 + x0] : 0.f;
            const float v01 = (xv1 & yv0) ? xb[y0 * 26 + x1] : 0.f;
            const float v10 = (xv0 & yv1) ? xb[y1 * 26 + x0] : 0.f;
            const float v11 = (xv1 & yv1) ? xb[y1 * 26 + x1] : 0.f;
            const float val = wy0 * (wx0 * v00 + wx1 * v01) + wy1 * (wx0 * v10 + wx1 * v11);
            kvT[j * 264 + c] = (unsigned short)f2bf(val);
        }
    }
    for (int u = tid; u < 684; u += 512) {
        if (u < 468) {
            const int ixv = u / 18, j = u - ixv * 18;
            const float p0 = (float)ixv * (2.0f / 11.0f) - 1.0f - n0_s[j];
            F0[u] = copysignf(__logf(1.0f + fabsf(p0)), p0);
        } else {
            const int u2 = u - 468;
            const int iyv = u2 / 18, j = u2 - iyv * 18;
            const float p1 = (float)iyv * (2.0f / 25.0f) - 1.0f - n1_s[j];
            F1[u2] = copysignf(__logf(1.0f + fabsf(p1)), p1);
        }
    }
    __syncthreads();

    // ---- k/v projection via MFMA: wave w -> matrix (w&1), mtb = w>>1 ----
    {
        const int m2 = w & 1, mtb = w >> 1;
        floatx4 pa[4][2];
        #pragma unroll
        for (int a = 0; a < 4; ++a) {
            pa[a][0] = (floatx4){0.f, 0.f, 0.f, 0.f};
            pa[a][1] = (floatx4){0.f, 0.f, 0.f, 0.f};
        }
        for (int ks = 0; ks < 8; ++ks) {
            U16 b0, b1;
            b0.u = *(const uint4*)(kvT + n * 264 + ks * 32 + qd * 8);
            b1.u = make_uint4(0u, 0u, 0u, 0u);
            if (n < 2) b1.u = *(const uint4*)(kvT + (16 + n) * 264 + ks * 32 + qd * 8);
            #pragma unroll
            for (int mtl = 0; mtl < 4; ++mtl) {
                const int mt = mtb + mtl * 4;
                U16 A; A.u = ws4[m2 * 8192 + mt * 512 + ks * 64 + lane];
                pa[mtl][0] = __builtin_amdgcn_mfma_f32_16x16x32_bf16(A.s, b0.s, pa[mtl][0], 0, 0, 0);
                pa[mtl][1] = __builtin_amdgcn_mfma_f32_16x16x32_bf16(A.s, b1.s, pa[mtl][1], 0, 0, 0);
            }
        }
        if (m2 == 0) {
            // k -> LDS bf16 (feeds Bk fragments)
            #pragma unroll
            for (int mtl = 0; mtl < 4; ++mtl) {
                const int mt = mtb + mtl * 4;
                #pragma unroll
                for (int r = 0; r < 4; ++r) {
                    const int o = mt * 16 + qd * 4 + r;
                    k_sb[o * 20 + n] = (unsigned short)f2bf(pa[mtl][0][r]);
                    if (n < 2) k_sb[o * 20 + 16 + n] = (unsigned short)f2bf(pa[mtl][1][r]);
                }
            }
        } else if (ib == 0) {
            // v -> ws fp32 (only one block per batch writes; k3 consumes)
            float* vdst = wsw + WSF_V + (size_t)b * 4608;
            #pragma unroll
            for (int mtl = 0; mtl < 4; ++mtl) {
                const int mt = mtb + mtl * 4;
                #pragma unroll
                for (int r = 0; r < 4; ++r) {
                    const int o = mt * 16 + qd * 4 + r;
                    vdst[o * 18 + n] = pa[mtl][0][r];
                    if (n < 2) vdst[o * 18 + 16 + n] = pa[mtl][1][r];
                }
            }
        }
    }
    __syncthreads();

    // ---- Bk fragments for sim (wave w: heads 2w, 2w+1) ----
    uint4 BkU[2][2];
    #pragma unroll
    for (int hh = 0; hh < 2; ++hh)
        #pragma unroll
        for (int jt = 0; jt < 2; ++jt) {
            unsigned int u0 = 0, u1 = 0, u2 = 0, u3 = 0;
            if (qd < 2 && (jt == 0 || n < 2)) {
                const int h = w * 2 + hh;
                const int j = jt * 16 + n;
                const int cb0 = (h * 16 + qd * 8) * 20 + j;
                u0 = (unsigned)k_sb[cb0] | ((unsigned)k_sb[cb0 + 20] << 16);
                u1 = (unsigned)k_sb[cb0 + 40] | ((unsigned)k_sb[cb0 + 60] << 16);
                u2 = (unsigned)k_sb[cb0 + 80] | ((unsigned)k_sb[cb0 + 100] << 16);
                u3 = (unsigned)k_sb[cb0 + 120] | ((unsigned)k_sb[cb0 + 140] << 16);
            }
            BkU[hh][jt] = make_uint4(u0, u1, u2, u3);
        }
    __syncthreads();   // k_sb dead; S_/h2w regions live from here

    // ---- chunk loop: 10 chunks of 16 i's over this block's half ----
    float wAcc[18];
    #pragma unroll
    for (int j = 0; j < 18; ++j) wAcc[j] = 0.f;

    for (int ch = 0; ch < 10; ++ch) {
        const int ibase = ib * 160 + ch * 16;
        const int CI = (312 - ibase < 16) ? (312 - ibase) : 16;
        if (CI <= 0) break;   // block-uniform

        // (a) sim: per wave 2 heads x 2 j-tiles -> S_[il][j][h]
        #pragma unroll
        for (int hh = 0; hh < 2; ++hh) {
            const int h = w * 2 + hh;
            unsigned int a0 = 0, a1 = 0, a2 = 0, a3u = 0;
            if (qd < 2) {
                const int base = h * 16 + qd * 8;
                a0 = (unsigned)q_sb[((base + 0) * 56 + ibase + n) & 255] |
                     ((unsigned)q_sb[((base + 1) * 56 + ibase + n) & 255] << 16);
                a1 = (unsigned)q_sb[((base + 2) * 56 + ibase + n) & 255] |
                     ((unsigned)q_sb[((base + 3) * 56 + ibase + n) & 255] << 16);
                a2 = (unsigned)q_sb[((base + 4) * 56 + ibase + n) & 255] |
                     ((unsigned)q_sb[((base + 5) * 56 + ibase + n) & 255] << 16);
                a3u = (unsigned)q_sb[((base + 6) * 56 + ibase + n) & 255] |
                      ((unsigned)q_sb[((base + 7) * 56 + ibase + n) & 255] << 16);
            }
            U16 Af; Af.u = make_uint4(a0, a1, a2, a3u);
            #pragma unroll
            for (int jt = 0; jt < 2; ++jt) {
                U16 Bf; Bf.u = BkU[hh][jt];
                floatx4 D = {0.f, 0.f, 0.f, 0.f};
                D = __builtin_amdgcn_mfma_f32_16x16x32_bf16(Af.s, Bf.s, D, 0, 0, 0);
                const int j = jt * 16 + n;
                if (j < 18) {
                    #pragma unroll
                    for (int r = 0; r < 4; ++r)
                        S_[((qd * 4 + r) * 18 + j) * 17 + h] = D[r];
                }
            }
        }
        __syncthreads();

        // (b) CPB MLP + logits, n-tile = one j; lanes n = il
        {
            const int i0 = ibase + n;
            const unsigned int lv = lutxy[i0 < 312 ? i0 : 311];
            const int ix = (int)(lv & 0xffffu), iy = (int)(lv >> 16);
            for (int nt = w; nt < 18; nt += 8) {
                const float f0 = F0[ix * 18 + nt];
                const float f1 = F1[iy * 18 + nt];
                unsigned int uu[8];
                #pragma unroll
                for (int kp = 0; kp < 8; ++kp) {
                    const float ha = fmaxf(fmaf(W1a[2 * kp], f0, fmaf(W1b[2 * kp], f1, B1r[2 * kp])), 0.f);
                    const float hb = fmaxf(fmaf(W1a[2 * kp + 1], f0, fmaf(W1b[2 * kp + 1], f1, B1r[2 * kp + 1])), 0.f);
                    uu[kp] = pk2(ha, hb);
                }
                U16 ub0, ub1;
                ub0.u = make_uint4(uu[0], uu[1], uu[2], uu[3]);
                ub1.u = make_uint4(uu[4], uu[5], uu[6], uu[7]);
                unsigned int* hw = h2w + w * 576 + n * 36;
                #pragma unroll
                for (int mtl = 0; mtl < 4; ++mtl) {
                    U16 A0, A1; A0.u = W2f[mtl][0]; A1.u = W2f[mtl][1];
                    floatx4 acc = {0.f, 0.f, 0.f, 0.f};
                    acc = __builtin_amdgcn_mfma_f32_16x16x32_bf16(A0.s, ub0.s, acc, 0, 0, 0);
                    acc = __builtin_amdgcn_mfma_f32_16x16x32_bf16(A1.s, ub1.s, acc, 0, 0, 0);
                    const float e0 = fmaxf(acc[0] + b2_s[mtl * 16 + qd * 4 + 0], 0.f);
                    const float e1 = fmaxf(acc[1] + b2_s[mtl * 16 + qd * 4 + 1], 0.f);
                    const float e2 = fmaxf(acc[2] + b2_s[mtl * 16 + qd * 4 + 2], 0.f);
                    const float e3 = fmaxf(acc[3] + b2_s[mtl * 16 + qd * 4 + 3], 0.f);
                    hw[mtl * 8 + qd * 2]     = pk2(e0, e1);
                    hw[mtl * 8 + qd * 2 + 1] = pk2(e2, e3);
                }
                U16 uc0, uc1;
                uc0.u = *(const uint4*)(hw + qd * 4);
                uc1.u = *(const uint4*)(hw + 16 + qd * 4);
                floatx4 a3 = {0.f, 0.f, 0.f, 0.f};
                {
                    U16 A0, A1; A0.u = W3f[0]; A1.u = W3f[1];
                    a3 = __builtin_amdgcn_mfma_f32_16x16x32_bf16(A0.s, uc0.s, a3, 0, 0, 0);
                    a3 = __builtin_amdgcn_mfma_f32_16x16x32_bf16(A1.s, uc1.s, a3, 0, 0, 0);
                }
                float* sp = S_ + (n * 18 + nt) * 17 + qd * 4;
                #pragma unroll
                for (int r = 0; r < 4; ++r) sp[r] = a3[r] + b3_s[qd * 4 + r] + sp[r];
            }
        }
        __syncthreads();

        // (c) softmax over j + conv-weighted accumulation (256 threads)
        if (tid < 256) {
            const int il = tid >> 4, h = tid & 15;
            if (il < CI) {
                float lv[18];
                #pragma unroll
                for (int j = 0; j < 18; ++j) lv[j] = S_[(il * 18 + j) * 17 + h];
                float m = lv[0];
                #pragma unroll
                for (int j = 1; j < 18; ++j) m = fmaxf(m, lv[j]);
                float s = 0.f;
                #pragma unroll
                for (int j = 0; j < 18; ++j) { lv[j] = __expf(lv[j] - m); s += lv[j]; }
                const float wgt = conv_w[ibase + il] / s;
                #pragma unroll
                for (int j = 0; j < 18; ++j) wAcc[j] = fmaf(wgt, lv[j], wAcc[j]);
            }
        }
        __syncthreads();
    }

    // ---- reduce wAcc over 16 il-slots -> atomicAdd partial wA to ws ----
    if (tid < 256) {
        const int slot = tid >> 4, h = tid & 15;
        #pragma unroll
        for (int j = 0; j < 18; ++j) wred[(slot * 16 + h) * 18 + j] = wAcc[j];
    }
    __syncthreads();
    for (int u = tid; u < 288; u += 512) {
        const int h = u / 18, j = u - h * 18;
        float s = 0.f;
        #pragma unroll
        for (int sl = 0; sl < 16; ++sl) s += wred[(sl * 16 + h) * 18 + j];
        atomicAdd(&wsw[WSF_WA + b * 288 + u], s);
    }
}

// ===========================================================================
// k3: m = wA . v ; pooled = w_out.m + b_out*S + conv_b ; +q ; LayerNorm
// ===========================================================================
__global__ __launch_bounds__(256) void k3_final(
    const float* __restrict__ q,
    const float* __restrict__ w_out, const float* __restrict__ b_out,
    const float* __restrict__ conv_w, const float* __restrict__ conv_b,
    const float* __restrict__ ln_g, const float* __restrict__ ln_b,
    const float* __restrict__ ws, float* __restrict__ out)
{
    const int b = blockIdx.x, tid = threadIdx.x;
    __shared__ float wA_s[288];
    __shared__ __align__(16) float m_s[256];
    __shared__ float redS[4], redA[4], redB[4];

    for (int i = tid; i < 288; i += 256) wA_s[i] = ws[WSF_WA + b * 288 + i];
    __syncthreads();

    {
        const int c = tid;
        const float* vr = ws + WSF_V + (size_t)b * 4608 + c * 18;
        const float* wr = &wA_s[(c >> 4) * 18];
        float acc = 0.f;
        #pragma unroll
        for (int j = 0; j < 18; ++j) acc += wr[j] * vr[j];
        m_s[c] = acc;
    }
    {
        float sp = conv_w[tid] + ((tid + 256) < 312 ? conv_w[tid + 256] : 0.f);
        for (int d = 32; d > 0; d >>= 1) sp += __shfl_down(sp, d, 64);
        if ((tid & 63) == 0) redS[tid >> 6] = sp;
    }
    __syncthreads();
    const float S = redS[0] + redS[1] + redS[2] + redS[3];

    const int o = tid;
    float acc = b_out[o] * S + conv_b[0];
    const float4* wor = (const float4*)(w_out + o * 256);
    const float4* m4 = (const float4*)m_s;
    for (int c4 = 0; c4 < 64; ++c4) {
        const float4 wq = wor[c4];
        const float4 mq = m4[c4];
        acc += wq.x * mq.x + wq.y * mq.y + wq.z * mq.z + wq.w * mq.w;
    }
    const float y = acc + q[b * 256 + o];

    float s1 = y, s2 = y * y;
    for (int d = 32; d > 0; d >>= 1) {
        s1 += __shfl_down(s1, d, 64);
        s2 += __shfl_down(s2, d, 64);
    }
    if ((tid & 63) == 0) { redA[tid >> 6] = s1; redB[tid >> 6] = s2; }
    __syncthreads();
    const float S1 = redA[0] + redA[1] + redA[2] + redA[3];
    const float S2 = redB[0] + redB[1] + redB[2] + redB[3];
    const float mu = S1 * (1.0f / 256.0f);
    const float var = S2 * (1.0f / 256.0f) - mu * mu;
    out[b * 256 + o] = (y - mu) * rsqrtf(var + 1e-5f) * ln_g[o] + ln_b[o];
}

// ===========================================================================
extern "C" void kernel_launch(void* const* d_in, const int* in_sizes, int n_in,
                              void* d_out, int out_size, void* d_ws, size_t ws_size,
                              hipStream_t stream) {
    const float* x       = (const float*)d_in[0];
    const float* q       = (const float*)d_in[1];
    const float* w_dw    = (const float*)d_in[2];
    const float* b_dwp   = (const float*)d_in[3];
    const float* w_pw    = (const float*)d_in[4];
    const float* wk      = (const float*)d_in[5];
    const float* wv      = (const float*)d_in[6];
    const float* w_out   = (const float*)d_in[7];
    const float* b_out   = (const float*)d_in[8];
    const float* cw1     = (const float*)d_in[9];
    const float* cb1     = (const float*)d_in[10];
    const float* cw2     = (const float*)d_in[11];
    const float* cb2     = (const float*)d_in[12];
    const float* cw3     = (const float*)d_in[13];
    const float* cb3     = (const float*)d_in[14];
    const float* conv_w  = (const float*)d_in[15];
    const float* conv_b  = (const float*)d_in[16];
    const float* ln_g    = (const float*)d_in[17];
    const float* ln_b    = (const float*)d_in[18];
    float* out = (float*)d_out;
    unsigned int* ws = (unsigned int*)d_ws;

    k0_setup<<<64, 256, 0, stream>>>(wk, wv, cw2, cw3, w_dw, ws);
    k_fused<<<dim3(2, 256), 512, 0, stream>>>(x, q, b_dwp, w_pw, cw1, cb1, cb2, cb3,
                                              conv_w, ws);
    k3_final<<<256, 256, 0, stream>>>(q, w_out, b_out, conv_w, conv_b, ln_g, ln_b,
                                      (const float*)ws, out);
}

// Round 6
// 268.925 us; speedup vs baseline: 1.7054x; 1.2669x over previous
//
#include <hip/hip_runtime.h>
#include <math.h>

// ---------------------------------------------------------------------------
// DIM=256 HEADS=16 DHEAD=16 H=12 W=26 (HW=312)  Hk=3 Wk=6 (J=18)  B=256
// q_map[b,c,s] = q[b,(c*56+s)&255]
// Round 6: ONE dispatch. grid 256 (block = batch) x 512 thr, LB(512,2).
//  - (512,2): r4 proved tighter wave bounds cap VGPRs and cause HBM spills.
//  - weights packed per-lane from global (L2-resident across blocks) - no k0.
//  - chunk=32 (30 barriers vs 60), shfl-based h2 transpose (no LDS roundtrip),
//    2-tile interleave in the MLP phase for latency overlap.
// ---------------------------------------------------------------------------

typedef __attribute__((ext_vector_type(8))) short short8;   // 8 bf16
typedef __attribute__((ext_vector_type(4))) float floatx4;

union U16 { uint4 u; short8 s; };

#define MFMA(A, B, C) __builtin_amdgcn_mfma_f32_16x16x32_bf16((A), (B), (C), 0, 0, 0)

__device__ __forceinline__ unsigned int f2bf(float f) {   // RNE f32->bf16 (low 16)
    unsigned int u = __float_as_uint(f);
    u += 0x7fffu + ((u >> 16) & 1u);
    return u >> 16;
}
__device__ __forceinline__ unsigned int pk2(float a, float b) {
    return f2bf(a) | (f2bf(b) << 16);
}
__device__ __forceinline__ float bf2f(unsigned short v) {
    return __uint_as_float((unsigned int)v << 16);
}
__device__ __forceinline__ uint4 pack8(float4 a, float4 b) {
    uint4 r;
    r.x = pk2(a.x, a.y); r.y = pk2(a.z, a.w);
    r.z = pk2(b.x, b.y); r.w = pk2(b.z, b.w);
    return r;
}

// ===========================================================================
__global__ __launch_bounds__(512, 2) void k_all(
    const float* __restrict__ x, const float* __restrict__ q,
    const float* __restrict__ w_dw, const float* __restrict__ b_dw,
    const float* __restrict__ w_pw,
    const float* __restrict__ wk, const float* __restrict__ wv,
    const float* __restrict__ w_out, const float* __restrict__ b_out,
    const float* __restrict__ cw1, const float* __restrict__ cb1,
    const float* __restrict__ cw2, const float* __restrict__ cb2,
    const float* __restrict__ cw3, const float* __restrict__ cb3,
    const float* __restrict__ conv_w, const float* __restrict__ conv_b,
    const float* __restrict__ ln_g, const float* __restrict__ ln_b,
    float* __restrict__ out)
{
    const int b = blockIdx.x, tid = threadIdx.x;
    const int w = tid >> 6, lane = tid & 63;
    const int n = lane & 15, qd = lane >> 4;

    // ---- persistent LDS (~19.9 KB) ----
    __shared__ float qf_s[256];
    __shared__ unsigned short q_sb[256];            // bf16(q*0.25)
    __shared__ unsigned short v_sb[5120];           // v bf16 [256][20]
    __shared__ float F0[468], F1[216];              // log tables [26][18], [12][18]
    __shared__ unsigned int lutxy[312];             // ix | iy<<16
    __shared__ float off_s[36], n0_s[18], n1_s[18];
    __shared__ float sx0[18], sy0[18], swx[18], swy[18];
    __shared__ float b2_s[64], b3_s[16];
    __shared__ float wA_s[288];
    __shared__ __align__(16) float m_s[256];
    __shared__ float pooled_s[256], redb[24];
    // ---- union region (39168 B) ----
    __shared__ __align__(16) unsigned char UB[39168];
    float* S_ = (float*)UB;                          // [32 il][18 j][17 h] 39168B
    unsigned short* kvT = (unsigned short*)UB;       // [18 j][264 c] bf16 9504B
    float* qsw = (float*)UB;                         // 16 copies x 258 = 16512B
    float* t_s = (float*)(UB + 16512);               // [18 p][256 c] 18432B
    unsigned short* k_sb = (unsigned short*)(UB + 16512);  // k bf16 [256][20]
    float* wred = (float*)UB;                        // [512 slot][18 j] 36864B

    // ---- per-lane weight fragments straight from global (L2-shared) ----
    uint4 W2f[4][2], W3f[2];
    {
        const float4* cw2_4 = (const float4*)cw2;
        #pragma unroll
        for (int mtl = 0; mtl < 4; ++mtl)
            #pragma unroll
            for (int ks = 0; ks < 2; ++ks) {
                const int base = (mtl * 16 + n) * 16 + ks * 8 + qd * 2;
                W2f[mtl][ks] = pack8(cw2_4[base], cw2_4[base + 1]);
            }
        const float4* cw3_4 = (const float4*)cw3;
        #pragma unroll
        for (int ks = 0; ks < 2; ++ks) {
            const int base = n * 16 + ks * 8 + qd * 2;
            W3f[ks] = pack8(cw3_4[base], cw3_4[base + 1]);
        }
    }
    float W1a[16], W1b[16], B1r[16];
    #pragma unroll
    for (int kk = 0; kk < 16; ++kk) {
        const int kid = (kk < 8) ? (qd * 8 + kk) : (32 + qd * 8 + kk - 8);
        W1a[kk] = cw1[kid * 2]; W1b[kk] = cw1[kid * 2 + 1]; B1r[kk] = cb1[kid];
    }

    // ---- stage 0 ----
    if (tid < 256) {
        const float qv = q[b * 256 + tid];
        qf_s[tid] = qv;
        q_sb[tid] = (unsigned short)f2bf(qv * 0.25f);
    }
    for (int u = tid; u < 4128; u += 512) {
        const int r = u / 258, i = u - r * 258;
        qsw[u] = (i < 256) ? q[b * 256 + i] : 0.f;
    }
    if (tid < 312) {
        const int iy = tid / 26;
        lutxy[tid] = (unsigned int)(tid - iy * 26) | ((unsigned int)iy << 16);
    }
    if (tid < 64) b2_s[tid] = cb2[tid];
    if (tid < 16) b3_s[tid] = cb3[tid];
    __syncthreads();

    // ---- depthwise conv 6x6 s4 p1 + GELU -> t_s ----
    {
        const int c = tid & 255, g = tid >> 8;     // g: jw-half
        float wreg[36];
        const float4* wdw4 = (const float4*)w_dw;  // [c][36] contiguous
        #pragma unroll
        for (int i = 0; i < 9; ++i) {
            const float4 t4 = wdw4[c * 9 + i];
            wreg[i * 4 + 0] = t4.x; wreg[i * 4 + 1] = t4.y;
            wreg[i * 4 + 2] = t4.z; wreg[i * 4 + 3] = t4.w;
        }
        float acc[9];
        const float bv = b_dw[c];
        #pragma unroll
        for (int a = 0; a < 9; ++a) acc[a] = bv;
        const int cb = (c * 56) & 255;
        const int cp = (c & 15) * 258;
        for (int jh = 0; jh < 3; ++jh) {
            for (int kh = 0; kh < 6; ++kh) {
                const int ih = jh * 4 - 1 + kh;
                if (ih < 0 || ih >= 12) continue;
                const int rb = ih * 26;
                #pragma unroll
                for (int jwl = 0; jwl < 3; ++jwl) {
                    const int jw = g * 3 + jwl;
                    #pragma unroll
                    for (int kw = 0; kw < 6; ++kw) {
                        const int iw = jw * 4 - 1 + kw;
                        if (iw < 0 || iw >= 26) continue;
                        acc[jh * 3 + jwl] += wreg[kh * 6 + kw] * qsw[cp + ((cb + rb + iw) & 255)];
                    }
                }
            }
        }
        #pragma unroll
        for (int a = 0; a < 9; ++a) {
            const int jh = a / 3, jwl = a - jh * 3;
            const int p = jh * 6 + g * 3 + jwl;
            const float v = acc[a];
            t_s[p * 256 + c] = 0.5f * v * (1.0f + erff(v * 0.70710678118654752f));
        }
    }
    __syncthreads();

    // ---- offsets: 36 dots over 256 channels ----
    for (int oi = w; oi < 36; oi += 8) {
        const int o = oi / 18, p = oi - o * 18;
        float s = 0.f;
        for (int c = lane; c < 256; c += 64) s += w_pw[o * 256 + c] * t_s[p * 256 + c];
        for (int d = 32; d > 0; d >>= 1) s += __shfl_down(s, d, 64);
        if (lane == 0) off_s[oi] = 4.0f * tanhf(s);
    }
    __syncthreads();

    // ---- grid coords + bilinear params ----
    if (tid < 18) {
        const int j = tid, jh = j / 6, jw = j - jh * 6;
        const float vg0 = (float)jw + off_s[j];
        const float vg1 = (float)jh + off_s[18 + j];
        const float n0 = 2.0f * vg0 / 2.0f - 1.0f;
        const float n1 = 2.0f * vg1 / 5.0f - 1.0f;
        n0_s[j] = n0; n1_s[j] = n1;
        const float xp = ((n0 + 1.0f) * 26.0f - 1.0f) * 0.5f;
        const float yp = ((n1 + 1.0f) * 12.0f - 1.0f) * 0.5f;
        const float x0 = floorf(xp), y0 = floorf(yp);
        sx0[j] = x0; sy0[j] = y0; swx[j] = xp - x0; swy[j] = yp - y0;
    }
    __syncthreads();

    // ---- bilinear sample -> kvT bf16 [j][264]; F0/F1 log tables ----
    {
        const int c = tid & 255, g = tid >> 8;
        const float* xb = x + ((size_t)b * 256 + c) * 312;
        for (int jj = 0; jj < 9; ++jj) {
            const int j = g * 9 + jj;
            const int x0 = (int)sx0[j], y0 = (int)sy0[j];
            const int x1 = x0 + 1, y1 = y0 + 1;
            const float wx1 = swx[j], wy1 = swy[j];
            const float wx0 = 1.f - wx1, wy0 = 1.f - wy1;
            const bool xv0 = (x0 >= 0) & (x0 < 26), xv1 = (x1 >= 0) & (x1 < 26);
            const bool yv0 = (y0 >= 0) & (y0 < 12), yv1 = (y1 >= 0) & (y1 < 12);
            const float v00 = (xv0 & yv0) ? xb[y0 * 26 + x0] : 0.f;
            const float v01 = (xv1 & yv0) ? xb[y0 * 26 + x1] : 0.f;
            const float v10 = (xv0 & yv1) ? xb[y1 * 26 + x0] : 0.f;
            const float v11 = (xv1 & yv1) ? xb[y1 * 26 + x1] : 0.f;
            const float val = wy0 * (wx0 * v00 + wx1 * v01) + wy1 * (wx0 * v10 + wx1 * v11);
            kvT[j * 264 + c] = (unsigned short)f2bf(val);
        }
    }
    for (int u = tid; u < 684; u += 512) {
        if (u < 468) {
            const int ixv = u / 18, j = u - ixv * 18;
            const float p0 = (float)ixv * (2.0f / 11.0f) - 1.0f - n0_s[j];
            F0[u] = copysignf(__logf(1.0f + fabsf(p0)), p0);
        } else {
            const int u2 = u - 468;
            const int iyv = u2 / 18, j = u2 - iyv * 18;
            const float p1 = (float)iyv * (2.0f / 25.0f) - 1.0f - n1_s[j];
            F1[u2] = copysignf(__logf(1.0f + fabsf(p1)), p1);
        }
    }
    __syncthreads();

    // ---- k/v projection via MFMA: wave w -> matrix (w&1), mtb = w>>1 ----
    {
        const int m2 = w & 1, mtb = w >> 1;
        const float4* wm4 = (const float4*)(m2 ? wv : wk);
        floatx4 pa[4][2];
        #pragma unroll
        for (int a = 0; a < 4; ++a) {
            pa[a][0] = (floatx4){0.f, 0.f, 0.f, 0.f};
            pa[a][1] = (floatx4){0.f, 0.f, 0.f, 0.f};
        }
        #pragma unroll 2
        for (int ks = 0; ks < 8; ++ks) {
            U16 b0, b1;
            b0.u = *(const uint4*)(kvT + n * 264 + ks * 32 + qd * 8);
            b1.u = make_uint4(0u, 0u, 0u, 0u);
            if (n < 2) b1.u = *(const uint4*)(kvT + (16 + n) * 264 + ks * 32 + qd * 8);
            #pragma unroll
            for (int mtl = 0; mtl < 4; ++mtl) {
                const int mt = mtb + mtl * 4;
                const int fb = (mt * 16 + n) * 16 + ks * 2 + qd * 2 * 1;  // see below
                // float index = (mt*16+n)*256 + ks*32 + qd*8  ->  float4 index:
                const int f4i = (mt * 16 + n) * 64 + ks * 8 + qd * 2;
                U16 A; A.u = pack8(wm4[f4i], wm4[f4i + 1]);
                (void)fb;
                pa[mtl][0] = MFMA(A.s, b0.s, pa[mtl][0]);
                pa[mtl][1] = MFMA(A.s, b1.s, pa[mtl][1]);
            }
        }
        unsigned short* dst = m2 ? v_sb : k_sb;
        #pragma unroll
        for (int mtl = 0; mtl < 4; ++mtl) {
            const int mt = mtb + mtl * 4;
            #pragma unroll
            for (int r = 0; r < 4; ++r) {
                const int o = mt * 16 + qd * 4 + r;
                dst[o * 20 + n] = (unsigned short)f2bf(pa[mtl][0][r]);
                if (n < 2) dst[o * 20 + 16 + n] = (unsigned short)f2bf(pa[mtl][1][r]);
            }
        }
    }
    __syncthreads();

    // ---- Bk fragments for sim (wave w: heads 2w, 2w+1) ----
    uint4 BkU[2][2];
    #pragma unroll
    for (int hh = 0; hh < 2; ++hh)
        #pragma unroll
        for (int jt = 0; jt < 2; ++jt) {
            unsigned int u0 = 0, u1 = 0, u2 = 0, u3 = 0;
            if (qd < 2 && (jt == 0 || n < 2)) {
                const int h = w * 2 + hh;
                const int j = jt * 16 + n;
                const int cb0 = (h * 16 + qd * 8) * 20 + j;
                u0 = (unsigned)k_sb[cb0] | ((unsigned)k_sb[cb0 + 20] << 16);
                u1 = (unsigned)k_sb[cb0 + 40] | ((unsigned)k_sb[cb0 + 60] << 16);
                u2 = (unsigned)k_sb[cb0 + 80] | ((unsigned)k_sb[cb0 + 100] << 16);
                u3 = (unsigned)k_sb[cb0 + 120] | ((unsigned)k_sb[cb0 + 140] << 16);
            }
            BkU[hh][jt] = make_uint4(u0, u1, u2, u3);
        }
    __syncthreads();   // k_sb dead; S_ region live from here

    // ---- chunk loop: 10 chunks of 32 i's (last 24) ----
    float wAcc[18];
    #pragma unroll
    for (int j = 0; j < 18; ++j) wAcc[j] = 0.f;

    const int srcA = n + ((lane & 16) << 1);   // n + 32*(qd&1)
    const int srcB = srcA + 16;
    const bool hi2 = (qd & 2) != 0;            // qd>>1 selector

    for (int ch = 0; ch < 10; ++ch) {
        const int ibase = ch * 32;
        const int CI = (ch == 9) ? 24 : 32;

        // (a) sim: wave w -> heads 2w,2w+1; 2 i-groups x 2 j-tiles
        #pragma unroll
        for (int hh = 0; hh < 2; ++hh) {
            const int h = w * 2 + hh;
            const int base = h * 16 + qd * 8;
            #pragma unroll
            for (int ig = 0; ig < 2; ++ig) {
                unsigned int a0 = 0, a1 = 0, a2 = 0, a3u = 0;
                if (qd < 2) {
                    const int ii = ibase + ig * 16 + n;
                    a0 = (unsigned)q_sb[((base + 0) * 56 + ii) & 255] |
                         ((unsigned)q_sb[((base + 1) * 56 + ii) & 255] << 16);
                    a1 = (unsigned)q_sb[((base + 2) * 56 + ii) & 255] |
                         ((unsigned)q_sb[((base + 3) * 56 + ii) & 255] << 16);
                    a2 = (unsigned)q_sb[((base + 4) * 56 + ii) & 255] |
                         ((unsigned)q_sb[((base + 5) * 56 + ii) & 255] << 16);
                    a3u = (unsigned)q_sb[((base + 6) * 56 + ii) & 255] |
                          ((unsigned)q_sb[((base + 7) * 56 + ii) & 255] << 16);
                }
                U16 Af; Af.u = make_uint4(a0, a1, a2, a3u);
                #pragma unroll
                for (int jt = 0; jt < 2; ++jt) {
                    U16 Bf; Bf.u = BkU[hh][jt];
                    floatx4 D = {0.f, 0.f, 0.f, 0.f};
                    D = MFMA(Af.s, Bf.s, D);
                    const int j = jt * 16 + n;
                    if (j < 18) {
                        #pragma unroll
                        for (int r = 0; r < 4; ++r)
                            S_[((ig * 16 + qd * 4 + r) * 18 + j) * 17 + h] = D[r];
                    }
                }
            }
        }
        __syncthreads();

        // (b) CPB MLP + logits; 36 tiles (ig,j), 2-tile interleaved per wave
        {
            auto mlp2 = [&](int tA, int tB, bool doB) {
                const int tv2[2] = {tA, tB};
                U16 ub0[2], ub1[2];
                #pragma unroll
                for (int u2 = 0; u2 < 2; ++u2) {
                    const int t = tv2[u2];
                    const int ig = (t >= 18) ? 1 : 0;
                    const int j = t - ig * 18;
                    const int i0 = ibase + ig * 16 + n;
                    const unsigned int lv = lutxy[(i0 < 312) ? i0 : 311];
                    const int ix = (int)(lv & 0xffffu), iy = (int)(lv >> 16);
                    const float f0 = F0[ix * 18 + j];
                    const float f1 = F1[iy * 18 + j];
                    unsigned int uu[8];
                    #pragma unroll
                    for (int kp = 0; kp < 8; ++kp) {
                        const float ha = fmaxf(fmaf(W1a[2*kp],   f0, fmaf(W1b[2*kp],   f1, B1r[2*kp])),   0.f);
                        const float hb = fmaxf(fmaf(W1a[2*kp+1], f0, fmaf(W1b[2*kp+1], f1, B1r[2*kp+1])), 0.f);
                        uu[kp] = pk2(ha, hb);
                    }
                    ub0[u2].u = make_uint4(uu[0], uu[1], uu[2], uu[3]);
                    ub1[u2].u = make_uint4(uu[4], uu[5], uu[6], uu[7]);
                }
                unsigned int Pa[2][4], Pb[2][4];
                #pragma unroll
                for (int u2 = 0; u2 < 2; ++u2) {
                    #pragma unroll
                    for (int mtl = 0; mtl < 4; ++mtl) {
                        U16 A0, A1; A0.u = W2f[mtl][0]; A1.u = W2f[mtl][1];
                        floatx4 acc = {0.f, 0.f, 0.f, 0.f};
                        acc = MFMA(A0.s, ub0[u2].s, acc);
                        acc = MFMA(A1.s, ub1[u2].s, acc);
                        const float e0 = fmaxf(acc[0] + b2_s[mtl*16 + qd*4 + 0], 0.f);
                        const float e1 = fmaxf(acc[1] + b2_s[mtl*16 + qd*4 + 1], 0.f);
                        const float e2 = fmaxf(acc[2] + b2_s[mtl*16 + qd*4 + 2], 0.f);
                        const float e3 = fmaxf(acc[3] + b2_s[mtl*16 + qd*4 + 3], 0.f);
                        Pa[u2][mtl] = pk2(e0, e1);
                        Pb[u2][mtl] = pk2(e2, e3);
                    }
                }
                #pragma unroll
                for (int u2 = 0; u2 < 2; ++u2) {
                    // in-wave transpose: h2 D-frag -> GEMM3 B-frag (no LDS)
                    unsigned int qa[4], qb[4], ra[4], rb[4];
                    #pragma unroll
                    for (int m = 0; m < 4; ++m) {
                        qa[m] = __shfl(Pa[u2][m], srcA, 64);
                        qb[m] = __shfl(Pb[u2][m], srcA, 64);
                        ra[m] = __shfl(Pa[u2][m], srcB, 64);
                        rb[m] = __shfl(Pb[u2][m], srcB, 64);
                    }
                    U16 uc0, uc1;
                    uc0.u = make_uint4(hi2 ? qa[1] : qa[0], hi2 ? qb[1] : qb[0],
                                       hi2 ? ra[1] : ra[0], hi2 ? rb[1] : rb[0]);
                    uc1.u = make_uint4(hi2 ? qa[3] : qa[2], hi2 ? qb[3] : qb[2],
                                       hi2 ? ra[3] : ra[2], hi2 ? rb[3] : rb[2]);
                    U16 A0, A1; A0.u = W3f[0]; A1.u = W3f[1];
                    floatx4 a3 = {0.f, 0.f, 0.f, 0.f};
                    a3 = MFMA(A0.s, uc0.s, a3);
                    a3 = MFMA(A1.s, uc1.s, a3);
                    if (u2 == 0 || doB) {
                        const int t = tv2[u2];
                        const int ig = (t >= 18) ? 1 : 0;
                        const int j = t - ig * 18;
                        float* sp = S_ + ((ig * 16 + n) * 18 + j) * 17 + qd * 4;
                        #pragma unroll
                        for (int r = 0; r < 4; ++r) sp[r] = a3[r] + b3_s[qd * 4 + r] + sp[r];
                    }
                }
            };
            mlp2(w, w + 8, true);
            mlp2(w + 16, w + 24, true);
            if (w < 4) mlp2(32 + w, 32 + w, false);
        }
        __syncthreads();

        // (c) softmax over j + conv-weighted accumulation (all 512 threads)
        {
            const int il = tid >> 4, h = tid & 15;
            if (il < CI) {
                float lv[18];
                #pragma unroll
                for (int j = 0; j < 18; ++j) lv[j] = S_[(il * 18 + j) * 17 + h];
                float m = lv[0];
                #pragma unroll
                for (int j = 1; j < 18; ++j) m = fmaxf(m, lv[j]);
                float s = 0.f;
                #pragma unroll
                for (int j = 0; j < 18; ++j) { lv[j] = __expf(lv[j] - m); s += lv[j]; }
                const float wgt = conv_w[ibase + il] / s;
                #pragma unroll
                for (int j = 0; j < 18; ++j) wAcc[j] = fmaf(wgt, lv[j], wAcc[j]);
            }
        }
        __syncthreads();
    }

    // ---- reduce wAcc over 32 il-slots -> wA_s[h][j]; conv_w sum ----
    #pragma unroll
    for (int j = 0; j < 18; ++j) wred[tid * 18 + j] = wAcc[j];
    {
        float v = 0.f;
        for (int u = tid; u < 312; u += 512) v += conv_w[u];
        for (int d = 32; d > 0; d >>= 1) v += __shfl_down(v, d, 64);
        if (lane == 0) redb[w] = v;
    }
    __syncthreads();
    for (int u = tid; u < 288; u += 512) {
        const int h = u / 18, j = u - h * 18;
        float s = 0.f;
        #pragma unroll
        for (int sl = 0; sl < 32; ++sl) s += wred[(sl * 16 + h) * 18 + j];
        wA_s[u] = s;
    }
    __syncthreads();

    // ---- m[c] = sum_j wA[h][j] * v[c][j] ----
    if (tid < 256) {
        const int hb = (tid >> 4) * 18;
        float acc = 0.f;
        #pragma unroll
        for (int j = 0; j < 18; ++j) acc += wA_s[hb + j] * bf2f(v_sb[tid * 20 + j]);
        m_s[tid] = acc;
    }
    __syncthreads();

    float Ssum = 0.f;
    #pragma unroll
    for (int i = 0; i < 8; ++i) Ssum += redb[i];

    // ---- pooled = w_out . m  (8 waves x 32 rows, coalesced float4) ----
    {
        const float4 mm = *(const float4*)(m_s + lane * 4);
        for (int ol = 0; ol < 32; ++ol) {
            const int o = w * 32 + ol;
            const float4 wq = *(const float4*)(w_out + o * 256 + lane * 4);
            float d = wq.x * mm.x + wq.y * mm.y + wq.z * mm.z + wq.w * mm.w;
            for (int dd = 32; dd > 0; dd >>= 1) d += __shfl_down(d, dd, 64);
            if (lane == 0) pooled_s[o] = d;
        }
    }
    __syncthreads();

    // ---- residual + LayerNorm (first 4 waves) ----
    if (tid < 256) {
        const float y = pooled_s[tid] + b_out[tid] * Ssum + conv_b[0] + qf_s[tid];
        float s1 = y, s2 = y * y;
        for (int d = 32; d > 0; d >>= 1) { s1 += __shfl_down(s1, d, 64); s2 += __shfl_down(s2, d, 64); }
        if (lane == 0) { redb[16 + w] = s1; redb[20 + w] = s2; }
    }
    __syncthreads();
    if (tid < 256) {
        const float y = pooled_s[tid] + b_out[tid] * Ssum + conv_b[0] + qf_s[tid];
        const float S1 = redb[16] + redb[17] + redb[18] + redb[19];
        const float S2 = redb[20] + redb[21] + redb[22] + redb[23];
        const float mu = S1 * (1.0f / 256.0f);
        const float var = S2 * (1.0f / 256.0f) - mu * mu;
        out[b * 256 + tid] = (y - mu) * rsqrtf(var + 1e-5f) * ln_g[tid] + ln_b[tid];
    }
}

// ===========================================================================
extern "C" void kernel_launch(void* const* d_in, const int* in_sizes, int n_in,
                              void* d_out, int out_size, void* d_ws, size_t ws_size,
                              hipStream_t stream) {
    const float* x       = (const float*)d_in[0];
    const float* q       = (const float*)d_in[1];
    const float* w_dw    = (const float*)d_in[2];
    const float* b_dwp   = (const float*)d_in[3];
    const float* w_pw    = (const float*)d_in[4];
    const float* wk      = (const float*)d_in[5];
    const float* wv      = (const float*)d_in[6];
    const float* w_out   = (const float*)d_in[7];
    const float* b_out   = (const float*)d_in[8];
    const float* cw1     = (const float*)d_in[9];
    const float* cb1     = (const float*)d_in[10];
    const float* cw2     = (const float*)d_in[11];
    const float* cb2     = (const float*)d_in[12];
    const float* cw3     = (const float*)d_in[13];
    const float* cb3     = (const float*)d_in[14];
    const float* conv_w  = (const float*)d_in[15];
    const float* conv_b  = (const float*)d_in[16];
    const float* ln_g    = (const float*)d_in[17];
    const float* ln_b    = (const float*)d_in[18];
    float* out = (float*)d_out;

    k_all<<<256, 512, 0, stream>>>(x, q, w_dw, b_dwp, w_pw, wk, wv, w_out, b_out,
                                   cw1, cb1, cw2, cb2, cw3, cb3,
                                   conv_w, conv_b, ln_g, ln_b, out);
}

// Round 7
// 265.446 us; speedup vs baseline: 1.7277x; 1.0131x over previous
//
#include <hip/hip_runtime.h>
#include <hip/hip_bf16.h>
#include <math.h>

// ---------------------------------------------------------------------------
// DIM=256 HEADS=16 DHEAD=16 H=12 W=26 (HW=312)  Hk=3 Wk=6 (J=18)  B=256
// q_map[b,c,s] = q[b,(c*56+s)&255]
// Round 7: ONE dispatch, grid 256 x 512 thr, LB(512,2) (r4: tighter bounds
// cause VGPR-cap spills). Changes vs r6:
//  - chunk loop software-pipelined: sim(ch) || softmax(ch-1) on double-
//    buffered S_ -> 2 barriers/chunk (was 3)
//  - h2 transpose back to LDS roundtrip (r6 shfl/bpermute regressed), stride
//    34 uints (~2-way banks = free), 2 regions/wave for cross-tile ILP
//  - bf16 packing via v_cvt_pk_bf16_f32 (__float22bfloat162_rn)
// ---------------------------------------------------------------------------

typedef __attribute__((ext_vector_type(8))) short short8;   // 8 bf16
typedef __attribute__((ext_vector_type(4))) float floatx4;

union U16 { uint4 u; short8 s; };

#define MFMA(A, B, C) __builtin_amdgcn_mfma_f32_16x16x32_bf16((A), (B), (C), 0, 0, 0)

__device__ __forceinline__ unsigned int f2bf(float f) {   // RNE f32->bf16 (low 16)
    unsigned int u = __float_as_uint(f);
    u += 0x7fffu + ((u >> 16) & 1u);
    return u >> 16;
}
__device__ __forceinline__ unsigned int pk2(float a, float b) {   // HW cvt_pk
    __hip_bfloat162 h = __float22bfloat162_rn(make_float2(a, b));
    union { __hip_bfloat162 h; unsigned int u; } cv; cv.h = h;
    return cv.u;
}
__device__ __forceinline__ float bf2f(unsigned short v) {
    return __uint_as_float((unsigned int)v << 16);
}
__device__ __forceinline__ uint4 pack8(float4 a, float4 b) {
    uint4 r;
    r.x = pk2(a.x, a.y); r.y = pk2(a.z, a.w);
    r.z = pk2(b.x, b.y); r.w = pk2(b.z, b.w);
    return r;
}

// ===========================================================================
__global__ __launch_bounds__(512, 2) void k_all(
    const float* __restrict__ x, const float* __restrict__ q,
    const float* __restrict__ w_dw, const float* __restrict__ b_dw,
    const float* __restrict__ w_pw,
    const float* __restrict__ wk, const float* __restrict__ wv,
    const float* __restrict__ w_out, const float* __restrict__ b_out,
    const float* __restrict__ cw1, const float* __restrict__ cb1,
    const float* __restrict__ cw2, const float* __restrict__ cb2,
    const float* __restrict__ cw3, const float* __restrict__ cb3,
    const float* __restrict__ conv_w, const float* __restrict__ conv_b,
    const float* __restrict__ ln_g, const float* __restrict__ ln_b,
    float* __restrict__ out)
{
    const int b = blockIdx.x, tid = threadIdx.x;
    const int w = tid >> 6, lane = tid & 63;
    const int n = lane & 15, qd = lane >> 4;

    // ---- persistent LDS (~19.9 KB) ----
    __shared__ float qf_s[256];
    __shared__ unsigned short q_sb[256];            // bf16(q*0.25)
    __shared__ unsigned short v_sb[5120];           // v bf16 [256][20]
    __shared__ float F0[468], F1[216];              // log tables [26][18], [12][18]
    __shared__ unsigned int lutxy[312];             // ix | iy<<16
    __shared__ float off_s[36], n0_s[18], n1_s[18];
    __shared__ float sx0[18], sy0[18], swx[18], swy[18];
    __shared__ float b2_s[64], b3_s[16];
    __shared__ float wA_s[288];
    __shared__ __align__(16) float m_s[256];
    __shared__ float pooled_s[256], redb[24];
    // ---- union region (113152 B) ----
    //   [0 .. 78336)  : S_ double buffer, 2 x [32 il][18 j][17 h] f32 (39168 B)
    //   [78336 .. end): h2w per-wave x2 regions [16][16 rows x 34 uints]
    __shared__ __align__(16) unsigned char UB[113152];
    float* Sbuf = (float*)UB;
    unsigned short* kvT = (unsigned short*)UB;       // [18 j][264 c] bf16 9504B
    float* qsw = (float*)UB;                         // 16 copies x 258 = 16512B
    float* t_s = (float*)(UB + 16512);               // [18 p][256 c] 18432B
    unsigned short* k_sb = (unsigned short*)(UB + 16512);  // k bf16 [256][20]
    unsigned int* h2w = (unsigned int*)(UB + 78336); // [16 region][544 uints]
    float* wred = (float*)UB;                        // [512 slot][18 j] 36864B

    // ---- per-lane weight fragments straight from global (L2-shared) ----
    uint4 W2f[4][2], W3f[2];
    {
        const float4* cw2_4 = (const float4*)cw2;
        #pragma unroll
        for (int mtl = 0; mtl < 4; ++mtl)
            #pragma unroll
            for (int ks = 0; ks < 2; ++ks) {
                const int base = (mtl * 16 + n) * 16 + ks * 8 + qd * 2;
                W2f[mtl][ks] = pack8(cw2_4[base], cw2_4[base + 1]);
            }
        const float4* cw3_4 = (const float4*)cw3;
        #pragma unroll
        for (int ks = 0; ks < 2; ++ks) {
            const int base = n * 16 + ks * 8 + qd * 2;
            W3f[ks] = pack8(cw3_4[base], cw3_4[base + 1]);
        }
    }
    float W1a[16], W1b[16], B1r[16];
    #pragma unroll
    for (int kk = 0; kk < 16; ++kk) {
        const int kid = (kk < 8) ? (qd * 8 + kk) : (32 + qd * 8 + kk - 8);
        W1a[kk] = cw1[kid * 2]; W1b[kk] = cw1[kid * 2 + 1]; B1r[kk] = cb1[kid];
    }

    // ---- stage 0 ----
    if (tid < 256) {
        const float qv = q[b * 256 + tid];
        qf_s[tid] = qv;
        q_sb[tid] = (unsigned short)f2bf(qv * 0.25f);
    }
    for (int u = tid; u < 4128; u += 512) {
        const int r = u / 258, i = u - r * 258;
        qsw[u] = (i < 256) ? q[b * 256 + i] : 0.f;
    }
    if (tid < 312) {
        const int iy = tid / 26;
        lutxy[tid] = (unsigned int)(tid - iy * 26) | ((unsigned int)iy << 16);
    }
    if (tid < 64) b2_s[tid] = cb2[tid];
    if (tid < 16) b3_s[tid] = cb3[tid];
    __syncthreads();

    // ---- depthwise conv 6x6 s4 p1 + GELU -> t_s ----
    {
        const int c = tid & 255, g = tid >> 8;     // g: jw-half
        float wreg[36];
        const float4* wdw4 = (const float4*)w_dw;  // [c][36] contiguous
        #pragma unroll
        for (int i = 0; i < 9; ++i) {
            const float4 t4 = wdw4[c * 9 + i];
            wreg[i * 4 + 0] = t4.x; wreg[i * 4 + 1] = t4.y;
            wreg[i * 4 + 2] = t4.z; wreg[i * 4 + 3] = t4.w;
        }
        float acc[9];
        const float bv = b_dw[c];
        #pragma unroll
        for (int a = 0; a < 9; ++a) acc[a] = bv;
        const int cb = (c * 56) & 255;
        const int cp = (c & 15) * 258;
        for (int jh = 0; jh < 3; ++jh) {
            for (int kh = 0; kh < 6; ++kh) {
                const int ih = jh * 4 - 1 + kh;
                if (ih < 0 || ih >= 12) continue;
                const int rb = ih * 26;
                #pragma unroll
                for (int jwl = 0; jwl < 3; ++jwl) {
                    const int jw = g * 3 + jwl;
                    #pragma unroll
                    for (int kw = 0; kw < 6; ++kw) {
                        const int iw = jw * 4 - 1 + kw;
                        if (iw < 0 || iw >= 26) continue;
                        acc[jh * 3 + jwl] += wreg[kh * 6 + kw] * qsw[cp + ((cb + rb + iw) & 255)];
                    }
                }
            }
        }
        #pragma unroll
        for (int a = 0; a < 9; ++a) {
            const int jh = a / 3, jwl = a - jh * 3;
            const int p = jh * 6 + g * 3 + jwl;
            const float v = acc[a];
            t_s[p * 256 + c] = 0.5f * v * (1.0f + erff(v * 0.70710678118654752f));
        }
    }
    __syncthreads();

    // ---- offsets: 36 dots over 256 channels ----
    for (int oi = w; oi < 36; oi += 8) {
        const int o = oi / 18, p = oi - o * 18;
        float s = 0.f;
        for (int c = lane; c < 256; c += 64) s += w_pw[o * 256 + c] * t_s[p * 256 + c];
        for (int d = 32; d > 0; d >>= 1) s += __shfl_down(s, d, 64);
        if (lane == 0) off_s[oi] = 4.0f * tanhf(s);
    }
    __syncthreads();

    // ---- grid coords + bilinear params ----
    if (tid < 18) {
        const int j = tid, jh = j / 6, jw = j - jh * 6;
        const float vg0 = (float)jw + off_s[j];
        const float vg1 = (float)jh + off_s[18 + j];
        const float n0 = 2.0f * vg0 / 2.0f - 1.0f;
        const float n1 = 2.0f * vg1 / 5.0f - 1.0f;
        n0_s[j] = n0; n1_s[j] = n1;
        const float xp = ((n0 + 1.0f) * 26.0f - 1.0f) * 0.5f;
        const float yp = ((n1 + 1.0f) * 12.0f - 1.0f) * 0.5f;
        const float x0 = floorf(xp), y0 = floorf(yp);
        sx0[j] = x0; sy0[j] = y0; swx[j] = xp - x0; swy[j] = yp - y0;
    }
    __syncthreads();

    // ---- bilinear sample -> kvT bf16 [j][264]; F0/F1 log tables ----
    {
        const int c = tid & 255, g = tid >> 8;
        const float* xb = x + ((size_t)b * 256 + c) * 312;
        for (int jj = 0; jj < 9; ++jj) {
            const int j = g * 9 + jj;
            const int x0 = (int)sx0[j], y0 = (int)sy0[j];
            const int x1 = x0 + 1, y1 = y0 + 1;
            const float wx1 = swx[j], wy1 = swy[j];
            const float wx0 = 1.f - wx1, wy0 = 1.f - wy1;
            const bool xv0 = (x0 >= 0) & (x0 < 26), xv1 = (x1 >= 0) & (x1 < 26);
            const bool yv0 = (y0 >= 0) & (y0 < 12), yv1 = (y1 >= 0) & (y1 < 12);
            const float v00 = (xv0 & yv0) ? xb[y0 * 26 + x0] : 0.f;
            const float v01 = (xv1 & yv0) ? xb[y0 * 26 + x1] : 0.f;
            const float v10 = (xv0 & yv1) ? xb[y1 * 26 + x0] : 0.f;
            const float v11 = (xv1 & yv1) ? xb[y1 * 26 + x1] : 0.f;
            const float val = wy0 * (wx0 * v00 + wx1 * v01) + wy1 * (wx0 * v10 + wx1 * v11);
            kvT[j * 264 + c] = (unsigned short)f2bf(val);
        }
    }
    for (int u = tid; u < 684; u += 512) {
        if (u < 468) {
            const int ixv = u / 18, j = u - ixv * 18;
            const float p0 = (float)ixv * (2.0f / 11.0f) - 1.0f - n0_s[j];
            F0[u] = copysignf(__logf(1.0f + fabsf(p0)), p0);
        } else {
            const int u2 = u - 468;
            const int iyv = u2 / 18, j = u2 - iyv * 18;
            const float p1 = (float)iyv * (2.0f / 25.0f) - 1.0f - n1_s[j];
            F1[u2] = copysignf(__logf(1.0f + fabsf(p1)), p1);
        }
    }
    __syncthreads();

    // ---- k/v projection via MFMA: wave w -> matrix (w&1), mtb = w>>1 ----
    {
        const int m2 = w & 1, mtb = w >> 1;
        const float4* wm4 = (const float4*)(m2 ? wv : wk);
        floatx4 pa[4][2];
        #pragma unroll
        for (int a = 0; a < 4; ++a) {
            pa[a][0] = (floatx4){0.f, 0.f, 0.f, 0.f};
            pa[a][1] = (floatx4){0.f, 0.f, 0.f, 0.f};
        }
        #pragma unroll 2
        for (int ks = 0; ks < 8; ++ks) {
            U16 b0, b1;
            b0.u = *(const uint4*)(kvT + n * 264 + ks * 32 + qd * 8);
            b1.u = make_uint4(0u, 0u, 0u, 0u);
            if (n < 2) b1.u = *(const uint4*)(kvT + (16 + n) * 264 + ks * 32 + qd * 8);
            #pragma unroll
            for (int mtl = 0; mtl < 4; ++mtl) {
                const int mt = mtb + mtl * 4;
                const int f4i = (mt * 16 + n) * 64 + ks * 8 + qd * 2;
                U16 A; A.u = pack8(wm4[f4i], wm4[f4i + 1]);
                pa[mtl][0] = MFMA(A.s, b0.s, pa[mtl][0]);
                pa[mtl][1] = MFMA(A.s, b1.s, pa[mtl][1]);
            }
        }
        unsigned short* dst = m2 ? v_sb : k_sb;
        #pragma unroll
        for (int mtl = 0; mtl < 4; ++mtl) {
            const int mt = mtb + mtl * 4;
            #pragma unroll
            for (int r = 0; r < 4; ++r) {
                const int o = mt * 16 + qd * 4 + r;
                dst[o * 20 + n] = (unsigned short)f2bf(pa[mtl][0][r]);
                if (n < 2) dst[o * 20 + 16 + n] = (unsigned short)f2bf(pa[mtl][1][r]);
            }
        }
    }
    __syncthreads();

    // ---- Bk fragments for sim (wave w: heads 2w, 2w+1) ----
    uint4 BkU[2][2];
    #pragma unroll
    for (int hh = 0; hh < 2; ++hh)
        #pragma unroll
        for (int jt = 0; jt < 2; ++jt) {
            unsigned int u0 = 0, u1 = 0, u2 = 0, u3 = 0;
            if (qd < 2 && (jt == 0 || n < 2)) {
                const int h = w * 2 + hh;
                const int j = jt * 16 + n;
                const int cb0 = (h * 16 + qd * 8) * 20 + j;
                u0 = (unsigned)k_sb[cb0] | ((unsigned)k_sb[cb0 + 20] << 16);
                u1 = (unsigned)k_sb[cb0 + 40] | ((unsigned)k_sb[cb0 + 60] << 16);
                u2 = (unsigned)k_sb[cb0 + 80] | ((unsigned)k_sb[cb0 + 100] << 16);
                u3 = (unsigned)k_sb[cb0 + 120] | ((unsigned)k_sb[cb0 + 140] << 16);
            }
            BkU[hh][jt] = make_uint4(u0, u1, u2, u3);
        }
    __syncthreads();   // k_sb dead; S_/h2w regions live from here

    // ---- pipelined chunk loop: 10 chunks of 32 i's (last 24) ----
    float wAcc[18];
    #pragma unroll
    for (int j = 0; j < 18; ++j) wAcc[j] = 0.f;

    // softmax + conv-weighted accumulation for chunk chp from buffer Sp
    auto soft_acc = [&](int chp, const float* Sp) {
        const int il = tid >> 4, h = tid & 15;
        const int CIp = (chp == 9) ? 24 : 32;
        if (il < CIp) {
            const float cwv = conv_w[chp * 32 + il];   // issued early, L2-hit
            float lv[18];
            #pragma unroll
            for (int j = 0; j < 18; ++j) lv[j] = Sp[(il * 18 + j) * 17 + h];
            float m = lv[0];
            #pragma unroll
            for (int j = 1; j < 18; ++j) m = fmaxf(m, lv[j]);
            float s = 0.f;
            #pragma unroll
            for (int j = 0; j < 18; ++j) { lv[j] = __expf(lv[j] - m); s += lv[j]; }
            const float wgt = cwv / s;
            #pragma unroll
            for (int j = 0; j < 18; ++j) wAcc[j] = fmaf(wgt, lv[j], wAcc[j]);
        }
    };

    for (int ch = 0; ch < 10; ++ch) {
        float* Sc = Sbuf + (ch & 1) * 9792;
        const float* Sp = Sbuf + ((ch & 1) ^ 1) * 9792;
        const int ibase = ch * 32;

        // (a) sim: wave w -> heads 2w,2w+1; 2 i-groups x 2 j-tiles -> Sc
        #pragma unroll
        for (int hh = 0; hh < 2; ++hh) {
            const int h = w * 2 + hh;
            const int base = h * 16 + qd * 8;
            #pragma unroll
            for (int ig = 0; ig < 2; ++ig) {
                unsigned int a0 = 0, a1 = 0, a2 = 0, a3u = 0;
                if (qd < 2) {
                    const int ii = ibase + ig * 16 + n;
                    a0 = (unsigned)q_sb[((base + 0) * 56 + ii) & 255] |
                         ((unsigned)q_sb[((base + 1) * 56 + ii) & 255] << 16);
                    a1 = (unsigned)q_sb[((base + 2) * 56 + ii) & 255] |
                         ((unsigned)q_sb[((base + 3) * 56 + ii) & 255] << 16);
                    a2 = (unsigned)q_sb[((base + 4) * 56 + ii) & 255] |
                         ((unsigned)q_sb[((base + 5) * 56 + ii) & 255] << 16);
                    a3u = (unsigned)q_sb[((base + 6) * 56 + ii) & 255] |
                          ((unsigned)q_sb[((base + 7) * 56 + ii) & 255] << 16);
                }
                U16 Af; Af.u = make_uint4(a0, a1, a2, a3u);
                #pragma unroll
                for (int jt = 0; jt < 2; ++jt) {
                    U16 Bf; Bf.u = BkU[hh][jt];
                    floatx4 D = {0.f, 0.f, 0.f, 0.f};
                    D = MFMA(Af.s, Bf.s, D);
                    const int j = jt * 16 + n;
                    if (j < 18) {
                        #pragma unroll
                        for (int r = 0; r < 4; ++r)
                            Sc[((ig * 16 + qd * 4 + r) * 18 + j) * 17 + h] = D[r];
                    }
                }
            }
        }
        // (c of ch-1) overlapped with (a): different buffer
        if (ch > 0) soft_acc(ch - 1, Sp);
        __syncthreads();

        // (b) CPB MLP + logits; 36 tiles, 2-tile interleave, LDS h2 roundtrip
        {
            auto mlp2 = [&](int tA, int tB, bool two) {
                const int tv2[2] = {tA, tB};
                U16 ub0[2], ub1[2];
                #pragma unroll
                for (int u2 = 0; u2 < 2; ++u2) {
                    const int t = tv2[u2];
                    const int ig = (t >= 18) ? 1 : 0;
                    const int j = t - ig * 18;
                    const int i0 = ibase + ig * 16 + n;
                    const unsigned int lv2 = lutxy[(i0 < 312) ? i0 : 311];
                    const int ix = (int)(lv2 & 0xffffu), iy = (int)(lv2 >> 16);
                    const float f0 = F0[ix * 18 + j];
                    const float f1 = F1[iy * 18 + j];
                    unsigned int uu[8];
                    #pragma unroll
                    for (int kp = 0; kp < 8; ++kp) {
                        const float ha = fmaxf(fmaf(W1a[2*kp],   f0, fmaf(W1b[2*kp],   f1, B1r[2*kp])),   0.f);
                        const float hb = fmaxf(fmaf(W1a[2*kp+1], f0, fmaf(W1b[2*kp+1], f1, B1r[2*kp+1])), 0.f);
                        uu[kp] = pk2(ha, hb);
                    }
                    ub0[u2].u = make_uint4(uu[0], uu[1], uu[2], uu[3]);
                    ub1[u2].u = make_uint4(uu[4], uu[5], uu[6], uu[7]);
                }
                // GEMM2 both tiles -> h2 to per-(wave,tile) LDS region
                #pragma unroll
                for (int u2 = 0; u2 < 2; ++u2) {
                    if (u2 == 1 && !two) break;
                    unsigned int* hw = h2w + ((w << 1) | u2) * 544 + n * 34;
                    #pragma unroll
                    for (int mtl = 0; mtl < 4; ++mtl) {
                        U16 A0, A1; A0.u = W2f[mtl][0]; A1.u = W2f[mtl][1];
                        floatx4 acc = {0.f, 0.f, 0.f, 0.f};
                        acc = MFMA(A0.s, ub0[u2].s, acc);
                        acc = MFMA(A1.s, ub1[u2].s, acc);
                        const float e0 = fmaxf(acc[0] + b2_s[mtl*16 + qd*4 + 0], 0.f);
                        const float e1 = fmaxf(acc[1] + b2_s[mtl*16 + qd*4 + 1], 0.f);
                        const float e2 = fmaxf(acc[2] + b2_s[mtl*16 + qd*4 + 2], 0.f);
                        const float e3 = fmaxf(acc[3] + b2_s[mtl*16 + qd*4 + 3], 0.f);
                        hw[mtl * 8 + qd * 2]     = pk2(e0, e1);
                        hw[mtl * 8 + qd * 2 + 1] = pk2(e2, e3);
                    }
                }
                // GEMM3 both tiles (single lgkm drain covers both regions)
                #pragma unroll
                for (int u2 = 0; u2 < 2; ++u2) {
                    if (u2 == 1 && !two) break;
                    const unsigned int* hwr = h2w + ((w << 1) | u2) * 544;
                    U16 uc0, uc1;
                    uc0.u = *(const uint4*)(hwr + n * 34 + qd * 4);
                    uc1.u = *(const uint4*)(hwr + n * 34 + 16 + qd * 4);
                    U16 A0, A1; A0.u = W3f[0]; A1.u = W3f[1];
                    floatx4 a3 = {0.f, 0.f, 0.f, 0.f};
                    a3 = MFMA(A0.s, uc0.s, a3);
                    a3 = MFMA(A1.s, uc1.s, a3);
                    const int t = tv2[u2];
                    const int ig = (t >= 18) ? 1 : 0;
                    const int j = t - ig * 18;
                    float* sp = Sc + ((ig * 16 + n) * 18 + j) * 17 + qd * 4;
                    #pragma unroll
                    for (int r = 0; r < 4; ++r) sp[r] = a3[r] + b3_s[qd * 4 + r] + sp[r];
                }
            };
            mlp2(w, w + 8, true);
            mlp2(w + 16, w + 24, true);
            if (w < 4) mlp2(32 + w, 32 + w, false);
        }
        __syncthreads();
    }
    // drain: softmax for final chunk (buffer 9&1 = 1)
    soft_acc(9, Sbuf + 9792);

    // ---- reduce wAcc over 32 il-slots -> wA_s[h][j]; conv_w sum ----
    // wred aliases S buffer 0 (36864B < 39168B); soft_acc(9) read buffer 1.
    #pragma unroll
    for (int j = 0; j < 18; ++j) wred[tid * 18 + j] = wAcc[j];
    {
        float v = 0.f;
        for (int u = tid; u < 312; u += 512) v += conv_w[u];
        for (int d = 32; d > 0; d >>= 1) v += __shfl_down(v, d, 64);
        if (lane == 0) redb[w] = v;
    }
    __syncthreads();
    for (int u = tid; u < 288; u += 512) {
        const int h = u / 18, j = u - h * 18;
        float s = 0.f;
        #pragma unroll
        for (int sl = 0; sl < 32; ++sl) s += wred[(sl * 16 + h) * 18 + j];
        wA_s[u] = s;
    }
    __syncthreads();

    // ---- m[c] = sum_j wA[h][j] * v[c][j] ----
    if (tid < 256) {
        const int hb = (tid >> 4) * 18;
        float acc = 0.f;
        #pragma unroll
        for (int j = 0; j < 18; ++j) acc += wA_s[hb + j] * bf2f(v_sb[tid * 20 + j]);
        m_s[tid] = acc;
    }
    __syncthreads();

    float Ssum = 0.f;
    #pragma unroll
    for (int i = 0; i < 8; ++i) Ssum += redb[i];

    // ---- pooled = w_out . m  (8 waves x 32 rows, coalesced float4) ----
    {
        const float4 mm = *(const float4*)(m_s + lane * 4);
        for (int ol = 0; ol < 32; ++ol) {
            const int o = w * 32 + ol;
            const float4 wq = *(const float4*)(w_out + o * 256 + lane * 4);
            float d = wq.x * mm.x + wq.y * mm.y + wq.z * mm.z + wq.w * mm.w;
            for (int dd = 32; dd > 0; dd >>= 1) d += __shfl_down(d, dd, 64);
            if (lane == 0) pooled_s[o] = d;
        }
    }
    __syncthreads();

    // ---- residual + LayerNorm (first 4 waves) ----
    if (tid < 256) {
        const float y = pooled_s[tid] + b_out[tid] * Ssum + conv_b[0] + qf_s[tid];
        float s1 = y, s2 = y * y;
        for (int d = 32; d > 0; d >>= 1) { s1 += __shfl_down(s1, d, 64); s2 += __shfl_down(s2, d, 64); }
        if (lane == 0) { redb[16 + w] = s1; redb[20 + w] = s2; }
    }
    __syncthreads();
    if (tid < 256) {
        const float y = pooled_s[tid] + b_out[tid] * Ssum + conv_b[0] + qf_s[tid];
        const float S1 = redb[16] + redb[17] + redb[18] + redb[19];
        const float S2 = redb[20] + redb[21] + redb[22] + redb[23];
        const float mu = S1 * (1.0f / 256.0f);
        const float var = S2 * (1.0f / 256.0f) - mu * mu;
        out[b * 256 + tid] = (y - mu) * rsqrtf(var + 1e-5f) * ln_g[tid] + ln_b[tid];
    }
}

// ===========================================================================
extern "C" void kernel_launch(void* const* d_in, const int* in_sizes, int n_in,
                              void* d_out, int out_size, void* d_ws, size_t ws_size,
                              hipStream_t stream) {
    const float* x       = (const float*)d_in[0];
    const float* q       = (const float*)d_in[1];
    const float* w_dw    = (const float*)d_in[2];
    const float* b_dwp   = (const float*)d_in[3];
    const float* w_pw    = (const float*)d_in[4];
    const float* wk      = (const float*)d_in[5];
    const float* wv      = (const float*)d_in[6];
    const float* w_out   = (const float*)d_in[7];
    const float* b_out   = (const float*)d_in[8];
    const float* cw1     = (const float*)d_in[9];
    const float* cb1     = (const float*)d_in[10];
    const float* cw2     = (const float*)d_in[11];
    const float* cb2     = (const float*)d_in[12];
    const float* cw3     = (const float*)d_in[13];
    const float* cb3     = (const float*)d_in[14];
    const float* conv_w  = (const float*)d_in[15];
    const float* conv_b  = (const float*)d_in[16];
    const float* ln_g    = (const float*)d_in[17];
    const float* ln_b    = (const float*)d_in[18];
    float* out = (float*)d_out;

    k_all<<<256, 512, 0, stream>>>(x, q, w_dw, b_dwp, w_pw, wk, wv, w_out, b_out,
                                   cw1, cb1, cw2, cb2, cw3, cb3,
                                   conv_w, conv_b, ln_g, ln_b, out);
}